// Round 5
// baseline (313.861 us; speedup 1.0000x reference)
//
#include <hip/hip_runtime.h>
#include <hip/hip_bf16.h>
#include <cstdint>
#include <cstddef>

typedef __bf16 bf16_t;
typedef bf16_t bf16x8 __attribute__((ext_vector_type(8)));
typedef float f32x4 __attribute__((ext_vector_type(4)));
typedef unsigned short ushort_t;

#define T_SEQ 2048
#define DM 1024
#define NH 16
#define HD 64
#define WIN 128
// LDS row stride for bf16 tiles accessed with b128 (bf16x8) ops: must be a
// multiple of 8 elements (16 B). 56 elem = 112 B; bank step 28/row -> 16-lane
// frag reads are 2-way bank-aliased (free on gfx950, m136).
#define LSTR 56
// ln(10000)/32
#define ROPE_C 0.28782313662425572f

__device__ __forceinline__ ushort_t f2bf(float f) {
    union { float f; unsigned u; } v; v.f = f;
    unsigned r = v.u + 0x7fff + ((v.u >> 16) & 1);
    return (ushort_t)(r >> 16);
}
// Diagnostic sentinel: passes finite values through untouched; replaces
// NaN/inf with `sent` so the test's absmax localizes a faulty stage.
__device__ __forceinline__ float sane(float v, float sent) {
    return (fabsf(v) < 1e30f) ? v : sent;
}

// ---------------------------------------------------------------------------
__global__ __launch_bounds__(256) void kzero_f(float* __restrict__ p) {
    size_t i = ((size_t)blockIdx.x * 256 + threadIdx.x) * 4;
    float4 z; z.x = z.y = z.z = z.w = 0.f;
    *(float4*)(p + i) = z;
}

// ---------------------------------------------------------------------------
// fp32 -> bf16 transpose: in[R][C] (float) -> out[C][R] (bf16). 64x64 tiles.
// ---------------------------------------------------------------------------
__global__ __launch_bounds__(256) void ktranspose_f2b(const float* __restrict__ in,
                                                      ushort_t* __restrict__ out,
                                                      int R, int C) {
    __shared__ __align__(16) ushort_t tile[64][72];
    const int c0 = blockIdx.x * 64, r0 = blockIdx.y * 64;
    const int tid = threadIdx.x;
    const int rl = tid >> 2, q4 = tid & 3;
    const float* src = in + (size_t)(r0 + rl) * C + c0 + q4 * 16;
    ushort_t cv[16];
#pragma unroll
    for (int i = 0; i < 4; i++) {
        float4 f = *(const float4*)(src + i * 4);
        cv[i * 4 + 0] = f2bf(f.x); cv[i * 4 + 1] = f2bf(f.y);
        cv[i * 4 + 2] = f2bf(f.z); cv[i * 4 + 3] = f2bf(f.w);
    }
    *(uint4*)&tile[rl][q4 * 16]     = *(uint4*)&cv[0];
    *(uint4*)&tile[rl][q4 * 16 + 8] = *(uint4*)&cv[8];
    __syncthreads();
    const int cl = tid >> 2;
    ushort_t tmp[16];
#pragma unroll
    for (int i = 0; i < 16; i++) tmp[i] = tile[q4 * 16 + i][cl];
    ushort_t* dst = out + (size_t)(c0 + cl) * R + r0 + q4 * 16;
    *(uint4*)(dst)     = *(uint4*)&tmp[0];
    *(uint4*)(dst + 8) = *(uint4*)&tmp[8];
}

// ---------------------------------------------------------------------------
// GEMM1 with fused RoPE + head split.
//   A = x [8192][1024] (fp32, converted to bf16 during staging)
//   Bt = WqkvT [3072][1024] (bf16)
//   cols [0,1024)->Qr (roped), [1024,2048)->Kr (roped), [2048,3072)->Vr
// ---------------------------------------------------------------------------
__global__ __launch_bounds__(256) void gemm_qkv(const float* __restrict__ A,
                                                const ushort_t* __restrict__ Bt,
                                                ushort_t* __restrict__ Qr,
                                                ushort_t* __restrict__ Kr,
                                                ushort_t* __restrict__ Vr) {
    __shared__ __align__(16) ushort_t As[128 * LSTR];
    __shared__ __align__(16) ushort_t Bs[128 * LSTR];
    const int m0 = blockIdx.x * 128, n0 = blockIdx.y * 128;
    const int tid = threadIdx.x;
    const int lane = tid & 63, w = tid >> 6;
    const int wm = (w & 1) * 64, wn = (w >> 1) * 64;
    const int c = lane & 15, g = lane >> 4;

    f32x4 acc[4][4];
#pragma unroll
    for (int mi = 0; mi < 4; mi++)
#pragma unroll
        for (int ni = 0; ni < 4; ni++)
#pragma unroll
            for (int r = 0; r < 4; r++) acc[mi][ni][r] = 0.f;

    for (int k0 = 0; k0 < 1024; k0 += 32) {
        __syncthreads();
#pragma unroll
        for (int i = 0; i < 2; i++) {
            int gr = tid + 256 * i;
            int row = gr >> 2, col8 = (gr & 3) * 8;
            // A: fp32 -> bf16 convert in registers, then 16B LDS store
            const float* ap = A + (size_t)(m0 + row) * 1024 + k0 + col8;
            float4 a0 = *(const float4*)(ap);
            float4 a1 = *(const float4*)(ap + 4);
            ushort_t cv[8];
            cv[0] = f2bf(a0.x); cv[1] = f2bf(a0.y); cv[2] = f2bf(a0.z); cv[3] = f2bf(a0.w);
            cv[4] = f2bf(a1.x); cv[5] = f2bf(a1.y); cv[6] = f2bf(a1.z); cv[7] = f2bf(a1.w);
            *(uint4*)&As[row * LSTR + col8] = *(uint4*)cv;
            // B: already bf16
            *(uint4*)&Bs[row * LSTR + col8] =
                *(const uint4*)(Bt + (size_t)(n0 + row) * 1024 + k0 + col8);
        }
        __syncthreads();
        bf16x8 af[4], bfr[4];
#pragma unroll
        for (int mi = 0; mi < 4; mi++)
            af[mi] = *(const bf16x8*)&As[(wm + mi * 16 + c) * LSTR + g * 8];
#pragma unroll
        for (int ni = 0; ni < 4; ni++)
            bfr[ni] = *(const bf16x8*)&Bs[(wn + ni * 16 + c) * LSTR + g * 8];
#pragma unroll
        for (int mi = 0; mi < 4; mi++)
#pragma unroll
            for (int ni = 0; ni < 4; ni++)
                acc[mi][ni] = __builtin_amdgcn_mfma_f32_16x16x32_bf16(
                    af[mi], bfr[ni], acc[mi][ni], 0, 0, 0);
    }

    const int nb = n0 + wn;             // 64-aligned wave column base
    const int sec = nb >> 10;           // 0=Q 1=K 2=V
    const int h = (nb >> 6) & 15;
    ushort_t* dst = (sec == 0) ? Qr : ((sec == 1) ? Kr : Vr);

    if (sec < 2) {
        const float invf0 = __expf(-(float)(c) * ROPE_C);        // pair i = c
        const float invf1 = __expf(-(float)(16 + c) * ROPE_C);   // pair i = 16+c
#pragma unroll
        for (int mi = 0; mi < 4; mi++)
#pragma unroll
            for (int r = 0; r < 4; r++) {
                int tg = m0 + wm + mi * 16 + g * 4 + r;
                int nB = tg >> 11, t = tg & (T_SEQ - 1);
                float s0, c0, s1, c1;
                sincosf((float)t * invf0, &s0, &c0);
                sincosf((float)t * invf1, &s1, &c1);
                size_t base = ((size_t)(nB * NH + h) * T_SEQ + t) * 64;
                float x1a = acc[mi][0][r], x2a = acc[mi][2][r];
                float x1b = acc[mi][1][r], x2b = acc[mi][3][r];
                dst[base + c]      = f2bf(sane(x1a * c0 - x2a * s0, 1e3f));
                dst[base + 16 + c] = f2bf(sane(x1b * c1 - x2b * s1, 1e3f));
                dst[base + 32 + c] = f2bf(sane(x1a * s0 + x2a * c0, 1e3f));
                dst[base + 48 + c] = f2bf(sane(x1b * s1 + x2b * c1, 1e3f));
            }
    } else {
#pragma unroll
        for (int mi = 0; mi < 4; mi++)
#pragma unroll
            for (int r = 0; r < 4; r++) {
                int tg = m0 + wm + mi * 16 + g * 4 + r;
                int nB = tg >> 11, t = tg & (T_SEQ - 1);
                size_t base = ((size_t)(nB * NH + h) * T_SEQ + t) * 64;
#pragma unroll
                for (int ni = 0; ni < 4; ni++)
                    dst[base + ni * 16 + c] = f2bf(sane(acc[mi][ni][r], 1e3f));
            }
    }
}

// ---------------------------------------------------------------------------
// V transpose: Vr[nh][t][64] -> Vt[nh][64][T] (bf16). grid (T/64, 64 heads).
// ---------------------------------------------------------------------------
__global__ __launch_bounds__(256) void vtrans(const ushort_t* __restrict__ Vr,
                                              ushort_t* __restrict__ Vt) {
    __shared__ __align__(16) ushort_t tile[64][72];
    const int t0 = blockIdx.x * 64, nh = blockIdx.y;
    const int tid = threadIdx.x, tl = tid >> 2, q4 = tid & 3;
    const ushort_t* src = Vr + ((size_t)nh * T_SEQ + t0 + tl) * 64 + q4 * 16;
    *(uint4*)&tile[tl][q4 * 16]     = *(const uint4*)(src);
    *(uint4*)&tile[tl][q4 * 16 + 8] = *(const uint4*)(src + 8);
    __syncthreads();
    const int d = tid >> 2;
    ushort_t tmp[16];
#pragma unroll
    for (int i = 0; i < 16; i++) tmp[i] = tile[q4 * 16 + i][d];
    ushort_t* dstp = Vt + ((size_t)nh * 64 + d) * T_SEQ + t0 + q4 * 16;
    *(uint4*)(dstp)     = *(uint4*)&tmp[0];
    *(uint4*)(dstp + 8) = *(uint4*)&tmp[8];
}

// ---------------------------------------------------------------------------
// Final projection: C[M][1024] (fp32) = A[M][1024] (bf16) * Bt^T (bf16) + bias.
// ---------------------------------------------------------------------------
__global__ __launch_bounds__(256) void gemm_out(const ushort_t* __restrict__ A,
                                                const ushort_t* __restrict__ Bt,
                                                float* __restrict__ C,
                                                const float* __restrict__ bias) {
    __shared__ __align__(16) ushort_t As[128 * LSTR];
    __shared__ __align__(16) ushort_t Bs[128 * LSTR];
    const int m0 = blockIdx.x * 128, n0 = blockIdx.y * 128;
    const int tid = threadIdx.x;
    const int lane = tid & 63, w = tid >> 6;
    const int wm = (w & 1) * 64, wn = (w >> 1) * 64;
    const int c = lane & 15, g = lane >> 4;

    f32x4 acc[4][4];
#pragma unroll
    for (int mi = 0; mi < 4; mi++)
#pragma unroll
        for (int ni = 0; ni < 4; ni++)
#pragma unroll
            for (int r = 0; r < 4; r++) acc[mi][ni][r] = 0.f;

    for (int k0 = 0; k0 < 1024; k0 += 32) {
        __syncthreads();
#pragma unroll
        for (int i = 0; i < 2; i++) {
            int gr = tid + 256 * i;
            int row = gr >> 2, col8 = (gr & 3) * 8;
            *(uint4*)&As[row * LSTR + col8] =
                *(const uint4*)(A + (size_t)(m0 + row) * 1024 + k0 + col8);
            *(uint4*)&Bs[row * LSTR + col8] =
                *(const uint4*)(Bt + (size_t)(n0 + row) * 1024 + k0 + col8);
        }
        __syncthreads();
        bf16x8 af[4], bfr[4];
#pragma unroll
        for (int mi = 0; mi < 4; mi++)
            af[mi] = *(const bf16x8*)&As[(wm + mi * 16 + c) * LSTR + g * 8];
#pragma unroll
        for (int ni = 0; ni < 4; ni++)
            bfr[ni] = *(const bf16x8*)&Bs[(wn + ni * 16 + c) * LSTR + g * 8];
#pragma unroll
        for (int mi = 0; mi < 4; mi++)
#pragma unroll
            for (int ni = 0; ni < 4; ni++)
                acc[mi][ni] = __builtin_amdgcn_mfma_f32_16x16x32_bf16(
                    af[mi], bfr[ni], acc[mi][ni], 0, 0, 0);
    }

#pragma unroll
    for (int ni = 0; ni < 4; ni++) {
        int col = n0 + wn + ni * 16 + c;
        float bv = bias[col];
#pragma unroll
        for (int mi = 0; mi < 4; mi++)
#pragma unroll
            for (int r = 0; r < 4; r++) {
                int rowi = m0 + wm + mi * 16 + g * 4 + r;
                C[(size_t)rowi * 1024 + col] = sane(acc[mi][ni][r] + bv, 1e8f);
            }
    }
}

// ---------------------------------------------------------------------------
// Sliding-window flash attention. 1 wave = 16 queries of one (n,h).
// Per-wave LDS P round-trip (C-layout -> A-layout); waves have different trip
// counts so __syncthreads is illegal -> explicit lgkmcnt fence + mem clobber.
// ---------------------------------------------------------------------------
__global__ __launch_bounds__(256) void attn_swin(const ushort_t* __restrict__ Qr,
                                                 const ushort_t* __restrict__ Kr,
                                                 const ushort_t* __restrict__ Vt,
                                                 ushort_t* __restrict__ O) {
    __shared__ __align__(16) ushort_t pbuf[4][16 * LSTR];
    const int wid = threadIdx.x >> 6, lane = threadIdx.x & 63;
    const int gid = blockIdx.x * 4 + wid;
    const int qt = gid & 127, h = (gid >> 7) & 15, n = gid >> 11;
    const int t0 = qt * 16;
    const int c = lane & 15, g = lane >> 4;
    const size_t hb = ((size_t)(n * NH + h)) * T_SEQ * 64;

    bf16x8 qf0 = *(const bf16x8*)(Qr + hb + (size_t)(t0 + c) * 64 + g * 8);
    bf16x8 qf1 = *(const bf16x8*)(Qr + hb + (size_t)(t0 + c) * 64 + 32 + g * 8);

    f32x4 o[4];
    float m_r[4], l_r[4];
#pragma unroll
    for (int i = 0; i < 4; i++) {
        m_r[i] = -1e30f; l_r[i] = 0.f;
#pragma unroll
        for (int r = 0; r < 4; r++) o[i][r] = 0.f;
    }

    int s_lo = (t0 - WIN) & ~31; if (s_lo < 0) s_lo = 0;
    int s_hi = t0 + 15 + WIN;    if (s_hi > T_SEQ - 1) s_hi = T_SEQ - 1;

    for (int s0 = s_lo; s0 <= s_hi; s0 += 32) {
        f32x4 S[2];
#pragma unroll
        for (int sh = 0; sh < 2; sh++) {
            int srow = s0 + sh * 16 + c;          // in [0,T) by construction
            bf16x8 kf0 = *(const bf16x8*)(Kr + hb + (size_t)srow * 64 + g * 8);
            bf16x8 kf1 = *(const bf16x8*)(Kr + hb + (size_t)srow * 64 + 32 + g * 8);
            f32x4 z;
#pragma unroll
            for (int r = 0; r < 4; r++) z[r] = 0.f;
            z = __builtin_amdgcn_mfma_f32_16x16x32_bf16(qf0, kf0, z, 0, 0, 0);
            z = __builtin_amdgcn_mfma_f32_16x16x32_bf16(qf1, kf1, z, 0, 0, 0);
            S[sh] = z;
        }
        float sv[2][4], rm[4];
#pragma unroll
        for (int r = 0; r < 4; r++) {
            int q = t0 + g * 4 + r;
            rm[r] = -1e30f;
#pragma unroll
            for (int sh = 0; sh < 2; sh++) {
                int s = s0 + sh * 16 + c;
                bool keep = (s - q >= -WIN) && (s - q <= WIN);
                float v = keep ? S[sh][r] * 0.125f : -1e30f;
                sv[sh][r] = v;
                rm[r] = fmaxf(rm[r], v);
            }
        }
#pragma unroll
        for (int off = 1; off < 16; off <<= 1)
#pragma unroll
            for (int r = 0; r < 4; r++) rm[r] = fmaxf(rm[r], __shfl_xor(rm[r], off, 64));
        float alpha[4], rs[4];
#pragma unroll
        for (int r = 0; r < 4; r++) {
            float mn = fmaxf(m_r[r], rm[r]);
            alpha[r] = __expf(m_r[r] - mn);
            m_r[r] = mn;
            rs[r] = 0.f;
        }
        ushort_t* pb = pbuf[wid];
#pragma unroll
        for (int sh = 0; sh < 2; sh++)
#pragma unroll
            for (int r = 0; r < 4; r++) {
                float p = (sv[sh][r] <= -1e29f) ? 0.f : __expf(sv[sh][r] - m_r[r]);
                rs[r] += p;
                pb[(g * 4 + r) * LSTR + sh * 16 + c] = f2bf(p);
            }
        __asm__ volatile("s_waitcnt lgkmcnt(0)" ::: "memory");
        bf16x8 pf = *(const bf16x8*)&pb[c * LSTR + g * 8];   // P in A-layout
        __asm__ volatile("" ::: "memory");  // keep next iter's stores below this load
#pragma unroll
        for (int off = 1; off < 16; off <<= 1)
#pragma unroll
            for (int r = 0; r < 4; r++) rs[r] += __shfl_xor(rs[r], off, 64);
#pragma unroll
        for (int r = 0; r < 4; r++) l_r[r] = l_r[r] * alpha[r] + rs[r];
#pragma unroll
        for (int di = 0; di < 4; di++)
#pragma unroll
            for (int r = 0; r < 4; r++) o[di][r] *= alpha[r];

        int sb = s0 + g * 8;
#pragma unroll
        for (int di = 0; di < 4; di++) {
            bf16x8 vf = *(const bf16x8*)(Vt + ((size_t)(n * NH + h) * 64 + di * 16 + c) * T_SEQ + sb);
            o[di] = __builtin_amdgcn_mfma_f32_16x16x32_bf16(pf, vf, o[di], 0, 0, 0);
        }
    }

#pragma unroll
    for (int di = 0; di < 4; di++)
#pragma unroll
        for (int r = 0; r < 4; r++) {
            int q = t0 + g * 4 + r;
            float val = o[di][r] / l_r[r];
            O[((size_t)(n * T_SEQ + q)) * DM + h * 64 + di * 16 + c] = f2bf(sane(val, 1e6f));
        }
}

// ---------------------------------------------------------------------------
extern "C" void kernel_launch(void* const* d_in, const int* in_sizes, int n_in,
                              void* d_out, int out_size, void* d_ws, size_t ws_size,
                              hipStream_t stream) {
    // Reference dtypes are float32 (setup_inputs uses jnp.float32).
    const float* x    = (const float*)d_in[0];
    const float* Wqkv = (const float*)d_in[1];
    const float* Wout = (const float*)d_in[2];
    const float* bout = (const float*)d_in[3];
    float* out = (float*)d_out;

    // Workspace (all bf16), peak 72 MB:
    //   0  .. 6  MB : WqkvT [3072][1024]
    //   6  .. 8  MB : WoutT [1024][1024]
    //   8  .. 24 MB : Qr [n][h][t][64]
    //   24 .. 40 MB : Kr
    //   40 .. 56 MB : Vr  (dead after vtrans; reused as Oat)
    //   56 .. 72 MB : Vt [n][h][64][T]
    const size_t NEED = 72ull << 20;
    if (ws_size < NEED) {
        kzero_f<<<dim3(8192), 256, 0, stream>>>(out);  // signature: absmax==ref
        return;
    }
    char* ws = (char*)d_ws;
    ushort_t* WqkvT = (ushort_t*)(ws);
    ushort_t* WoutT = (ushort_t*)(ws + (6ull << 20));
    ushort_t* Qr    = (ushort_t*)(ws + (8ull << 20));
    ushort_t* Kr    = (ushort_t*)(ws + (24ull << 20));
    ushort_t* Vr    = (ushort_t*)(ws + (40ull << 20));
    ushort_t* Vt    = (ushort_t*)(ws + (56ull << 20));
    ushort_t* Oat   = Vr;  // alias: Vr dead after vtrans

    ktranspose_f2b<<<dim3(48, 16), 256, 0, stream>>>(Wqkv, WqkvT, 1024, 3072);
    ktranspose_f2b<<<dim3(16, 16), 256, 0, stream>>>(Wout, WoutT, 1024, 1024);
    gemm_qkv<<<dim3(64, 24), 256, 0, stream>>>(x, WqkvT, Qr, Kr, Vr);
    vtrans<<<dim3(32, 64), 256, 0, stream>>>(Vr, Vt);
    attn_swin<<<dim3(2048), 256, 0, stream>>>(Qr, Kr, Vt, Oat);
    gemm_out<<<dim3(64, 8), 256, 0, stream>>>(Oat, WoutT, out, bout);
}

// Round 6
// 283.399 us; speedup vs baseline: 1.1075x; 1.1075x over previous
//
#include <hip/hip_runtime.h>
#include <hip/hip_bf16.h>
#include <cstdint>
#include <cstddef>

typedef __bf16 bf16_t;
typedef bf16_t bf16x8 __attribute__((ext_vector_type(8)));
typedef float f32x4 __attribute__((ext_vector_type(4)));
typedef unsigned short ushort_t;

#define T_SEQ 2048
#define DM 1024
#define NH 16
#define HD 64
#define WIN 128
// ln(10000)/32
#define ROPE_C 0.28782313662425572f
// (1/sqrt(64)) * log2(e) -- attention softmax in log2 domain
#define SCALE_LOG2E 0.18033688011112042f

__device__ __forceinline__ ushort_t f2bf(float f) {
    union { float f; unsigned u; } v; v.f = f;
    unsigned r = v.u + 0x7fff + ((v.u >> 16) & 1);
    return (ushort_t)(r >> 16);
}
__device__ __forceinline__ float sane(float v, float sent) {
    return (fabsf(v) < 1e30f) ? v : sent;
}
// Async global->LDS, 16 B per lane. LDS dest = wave-uniform base + lane*16.
__device__ __forceinline__ void gld16(const ushort_t* g, ushort_t* l) {
    __builtin_amdgcn_global_load_lds(
        (const __attribute__((address_space(1))) unsigned int*)g,
        (__attribute__((address_space(3))) unsigned int*)l, 16, 0, 0);
}

// ---------------------------------------------------------------------------
__global__ __launch_bounds__(256) void kzero_f(float* __restrict__ p) {
    size_t i = ((size_t)blockIdx.x * 256 + threadIdx.x) * 4;
    float4 z; z.x = z.y = z.z = z.w = 0.f;
    *(float4*)(p + i) = z;
}

// ---------------------------------------------------------------------------
// x fp32 -> bf16, flat copy. 8 elems/thread.
// ---------------------------------------------------------------------------
__global__ __launch_bounds__(256) void xcvt(const float* __restrict__ in,
                                            ushort_t* __restrict__ out) {
    size_t i = ((size_t)blockIdx.x * 256 + threadIdx.x) * 8;
    float4 a0 = *(const float4*)(in + i);
    float4 a1 = *(const float4*)(in + i + 4);
    ushort_t cv[8];
    cv[0] = f2bf(a0.x); cv[1] = f2bf(a0.y); cv[2] = f2bf(a0.z); cv[3] = f2bf(a0.w);
    cv[4] = f2bf(a1.x); cv[5] = f2bf(a1.y); cv[6] = f2bf(a1.z); cv[7] = f2bf(a1.w);
    *(uint4*)(out + i) = *(uint4*)cv;
}

// ---------------------------------------------------------------------------
// fp32 -> bf16 transpose: in[R][C] (float) -> out[C][R] (bf16). 64x64 tiles.
// ---------------------------------------------------------------------------
__global__ __launch_bounds__(256) void ktranspose_f2b(const float* __restrict__ in,
                                                      ushort_t* __restrict__ out,
                                                      int R, int C) {
    __shared__ __align__(16) ushort_t tile[64][72];
    const int c0 = blockIdx.x * 64, r0 = blockIdx.y * 64;
    const int tid = threadIdx.x;
    const int rl = tid >> 2, q4 = tid & 3;
    const float* src = in + (size_t)(r0 + rl) * C + c0 + q4 * 16;
    ushort_t cv[16];
#pragma unroll
    for (int i = 0; i < 4; i++) {
        float4 f = *(const float4*)(src + i * 4);
        cv[i * 4 + 0] = f2bf(f.x); cv[i * 4 + 1] = f2bf(f.y);
        cv[i * 4 + 2] = f2bf(f.z); cv[i * 4 + 3] = f2bf(f.w);
    }
    *(uint4*)&tile[rl][q4 * 16]     = *(uint4*)&cv[0];
    *(uint4*)&tile[rl][q4 * 16 + 8] = *(uint4*)&cv[8];
    __syncthreads();
    const int cl = tid >> 2;
    ushort_t tmp[16];
#pragma unroll
    for (int i = 0; i < 16; i++) tmp[i] = tile[q4 * 16 + i][cl];
    ushort_t* dst = out + (size_t)(c0 + cl) * R + r0 + q4 * 16;
    *(uint4*)(dst)     = *(uint4*)&tmp[0];
    *(uint4*)(dst + 8) = *(uint4*)&tmp[8];
}

// ---------------------------------------------------------------------------
// GEMM1 (m97 structure): C = xb[8192][1024] * WqkvT[3072][1024]^T with fused
// RoPE + head split epilogue. 128x128 tile, BK=32, global_load_lds staging
// into unpadded [128][32] LDS tiles (wave-uniform + lane*16 layout).
// ---------------------------------------------------------------------------
__global__ __launch_bounds__(256) void gemm_qkv(const ushort_t* __restrict__ A,
                                                const ushort_t* __restrict__ Bt,
                                                ushort_t* __restrict__ Qr,
                                                ushort_t* __restrict__ Kr,
                                                ushort_t* __restrict__ Vr) {
    __shared__ __align__(16) ushort_t As[128 * 32];
    __shared__ __align__(16) ushort_t Bs[128 * 32];
    const int m0 = blockIdx.x * 128, n0 = blockIdx.y * 128;
    const int tid = threadIdx.x;
    const int lane = tid & 63, w = tid >> 6;
    const int wm = (w & 1) * 64, wn = (w >> 1) * 64;
    const int c = lane & 15, g = lane >> 4;
    const int lrow = lane >> 2, lcol = (lane & 3) * 8;   // staging lane map
    const int ch0 = 2 * w, ch1 = 2 * w + 1;

    f32x4 acc[4][4];
#pragma unroll
    for (int mi = 0; mi < 4; mi++)
#pragma unroll
        for (int ni = 0; ni < 4; ni++)
#pragma unroll
            for (int r = 0; r < 4; r++) acc[mi][ni][r] = 0.f;

    for (int k0 = 0; k0 < 1024; k0 += 32) {
        __syncthreads();
        gld16(A  + (size_t)(m0 + ch0 * 16 + lrow) * 1024 + k0 + lcol, &As[ch0 * 512]);
        gld16(A  + (size_t)(m0 + ch1 * 16 + lrow) * 1024 + k0 + lcol, &As[ch1 * 512]);
        gld16(Bt + (size_t)(n0 + ch0 * 16 + lrow) * 1024 + k0 + lcol, &Bs[ch0 * 512]);
        gld16(Bt + (size_t)(n0 + ch1 * 16 + lrow) * 1024 + k0 + lcol, &Bs[ch1 * 512]);
        __syncthreads();
        bf16x8 af[4], bfr[4];
#pragma unroll
        for (int mi = 0; mi < 4; mi++)
            af[mi] = *(const bf16x8*)&As[(wm + mi * 16 + c) * 32 + g * 8];
#pragma unroll
        for (int ni = 0; ni < 4; ni++)
            bfr[ni] = *(const bf16x8*)&Bs[(wn + ni * 16 + c) * 32 + g * 8];
#pragma unroll
        for (int mi = 0; mi < 4; mi++)
#pragma unroll
            for (int ni = 0; ni < 4; ni++)
                acc[mi][ni] = __builtin_amdgcn_mfma_f32_16x16x32_bf16(
                    af[mi], bfr[ni], acc[mi][ni], 0, 0, 0);
    }

    const int nb = n0 + wn;             // 64-aligned wave column base
    const int sec = nb >> 10;           // 0=Q 1=K 2=V
    const int h = (nb >> 6) & 15;
    ushort_t* dst = (sec == 0) ? Qr : ((sec == 1) ? Kr : Vr);

    if (sec < 2) {
        const float invf0 = __expf(-(float)(c) * ROPE_C);        // pair i = c
        const float invf1 = __expf(-(float)(16 + c) * ROPE_C);   // pair i = 16+c
#pragma unroll
        for (int mi = 0; mi < 4; mi++)
#pragma unroll
            for (int r = 0; r < 4; r++) {
                int tg = m0 + wm + mi * 16 + g * 4 + r;
                int nB = tg >> 11, t = tg & (T_SEQ - 1);
                float s0, c0, s1, c1;
                sincosf((float)t * invf0, &s0, &c0);
                sincosf((float)t * invf1, &s1, &c1);
                size_t base = ((size_t)(nB * NH + h) * T_SEQ + t) * 64;
                float x1a = acc[mi][0][r], x2a = acc[mi][2][r];
                float x1b = acc[mi][1][r], x2b = acc[mi][3][r];
                dst[base + c]      = f2bf(sane(x1a * c0 - x2a * s0, 1e3f));
                dst[base + 16 + c] = f2bf(sane(x1b * c1 - x2b * s1, 1e3f));
                dst[base + 32 + c] = f2bf(sane(x1a * s0 + x2a * c0, 1e3f));
                dst[base + 48 + c] = f2bf(sane(x1b * s1 + x2b * c1, 1e3f));
            }
    } else {
#pragma unroll
        for (int mi = 0; mi < 4; mi++)
#pragma unroll
            for (int r = 0; r < 4; r++) {
                int tg = m0 + wm + mi * 16 + g * 4 + r;
                int nB = tg >> 11, t = tg & (T_SEQ - 1);
                size_t base = ((size_t)(nB * NH + h) * T_SEQ + t) * 64;
#pragma unroll
                for (int ni = 0; ni < 4; ni++)
                    dst[base + ni * 16 + c] = f2bf(sane(acc[mi][ni][r], 1e3f));
            }
    }
}

// ---------------------------------------------------------------------------
// V transpose: Vr[nh][t][64] -> Vt[nh][64][T] (bf16). grid (T/64, 64 heads).
// ---------------------------------------------------------------------------
__global__ __launch_bounds__(256) void vtrans(const ushort_t* __restrict__ Vr,
                                              ushort_t* __restrict__ Vt) {
    __shared__ __align__(16) ushort_t tile[64][72];
    const int t0 = blockIdx.x * 64, nh = blockIdx.y;
    const int tid = threadIdx.x, tl = tid >> 2, q4 = tid & 3;
    const ushort_t* src = Vr + ((size_t)nh * T_SEQ + t0 + tl) * 64 + q4 * 16;
    *(uint4*)&tile[tl][q4 * 16]     = *(const uint4*)(src);
    *(uint4*)&tile[tl][q4 * 16 + 8] = *(const uint4*)(src + 8);
    __syncthreads();
    const int d = tid >> 2;
    ushort_t tmp[16];
#pragma unroll
    for (int i = 0; i < 16; i++) tmp[i] = tile[q4 * 16 + i][d];
    ushort_t* dstp = Vt + ((size_t)nh * 64 + d) * T_SEQ + t0 + q4 * 16;
    *(uint4*)(dstp)     = *(uint4*)&tmp[0];
    *(uint4*)(dstp + 8) = *(uint4*)&tmp[8];
}

// ---------------------------------------------------------------------------
// Final projection (m97 structure): C[M][1024] fp32 = A bf16 * WoutT^T + bias.
// ---------------------------------------------------------------------------
__global__ __launch_bounds__(256) void gemm_out(const ushort_t* __restrict__ A,
                                                const ushort_t* __restrict__ Bt,
                                                float* __restrict__ C,
                                                const float* __restrict__ bias) {
    __shared__ __align__(16) ushort_t As[128 * 32];
    __shared__ __align__(16) ushort_t Bs[128 * 32];
    const int m0 = blockIdx.x * 128, n0 = blockIdx.y * 128;
    const int tid = threadIdx.x;
    const int lane = tid & 63, w = tid >> 6;
    const int wm = (w & 1) * 64, wn = (w >> 1) * 64;
    const int c = lane & 15, g = lane >> 4;
    const int lrow = lane >> 2, lcol = (lane & 3) * 8;
    const int ch0 = 2 * w, ch1 = 2 * w + 1;

    f32x4 acc[4][4];
#pragma unroll
    for (int mi = 0; mi < 4; mi++)
#pragma unroll
        for (int ni = 0; ni < 4; ni++)
#pragma unroll
            for (int r = 0; r < 4; r++) acc[mi][ni][r] = 0.f;

    for (int k0 = 0; k0 < 1024; k0 += 32) {
        __syncthreads();
        gld16(A  + (size_t)(m0 + ch0 * 16 + lrow) * 1024 + k0 + lcol, &As[ch0 * 512]);
        gld16(A  + (size_t)(m0 + ch1 * 16 + lrow) * 1024 + k0 + lcol, &As[ch1 * 512]);
        gld16(Bt + (size_t)(n0 + ch0 * 16 + lrow) * 1024 + k0 + lcol, &Bs[ch0 * 512]);
        gld16(Bt + (size_t)(n0 + ch1 * 16 + lrow) * 1024 + k0 + lcol, &Bs[ch1 * 512]);
        __syncthreads();
        bf16x8 af[4], bfr[4];
#pragma unroll
        for (int mi = 0; mi < 4; mi++)
            af[mi] = *(const bf16x8*)&As[(wm + mi * 16 + c) * 32 + g * 8];
#pragma unroll
        for (int ni = 0; ni < 4; ni++)
            bfr[ni] = *(const bf16x8*)&Bs[(wn + ni * 16 + c) * 32 + g * 8];
#pragma unroll
        for (int mi = 0; mi < 4; mi++)
#pragma unroll
            for (int ni = 0; ni < 4; ni++)
                acc[mi][ni] = __builtin_amdgcn_mfma_f32_16x16x32_bf16(
                    af[mi], bfr[ni], acc[mi][ni], 0, 0, 0);
    }

#pragma unroll
    for (int ni = 0; ni < 4; ni++) {
        int col = n0 + wn + ni * 16 + c;
        float bv = bias[col];
#pragma unroll
        for (int mi = 0; mi < 4; mi++)
#pragma unroll
            for (int r = 0; r < 4; r++) {
                int rowi = m0 + wm + mi * 16 + g * 4 + r;
                C[(size_t)rowi * 1024 + col] = sane(acc[mi][ni][r] + bv, 1e8f);
            }
    }
}

// ---------------------------------------------------------------------------
// Sliding-window flash attention. 1 wave = 16 queries of one (n,h).
// Softmax in log2 domain (v_exp_f32 native). Per-wave LDS P round-trip with
// explicit lgkmcnt fence (different trip counts -> no __syncthreads).
// ---------------------------------------------------------------------------
__global__ __launch_bounds__(256) void attn_swin(const ushort_t* __restrict__ Qr,
                                                 const ushort_t* __restrict__ Kr,
                                                 const ushort_t* __restrict__ Vt,
                                                 ushort_t* __restrict__ O) {
    __shared__ __align__(16) ushort_t pbuf[4][16 * 32];
    const int wid = threadIdx.x >> 6, lane = threadIdx.x & 63;
    const int gid = blockIdx.x * 4 + wid;
    const int qt = gid & 127, h = (gid >> 7) & 15, n = gid >> 11;
    const int t0 = qt * 16;
    const int c = lane & 15, g = lane >> 4;
    const size_t hb = ((size_t)(n * NH + h)) * T_SEQ * 64;

    bf16x8 qf0 = *(const bf16x8*)(Qr + hb + (size_t)(t0 + c) * 64 + g * 8);
    bf16x8 qf1 = *(const bf16x8*)(Qr + hb + (size_t)(t0 + c) * 64 + 32 + g * 8);

    f32x4 o[4];
    float m_r[4], l_r[4];
#pragma unroll
    for (int i = 0; i < 4; i++) {
        m_r[i] = -1e30f; l_r[i] = 0.f;
#pragma unroll
        for (int r = 0; r < 4; r++) o[i][r] = 0.f;
    }

    int s_lo = (t0 - WIN) & ~31; if (s_lo < 0) s_lo = 0;
    int s_hi = t0 + 15 + WIN;    if (s_hi > T_SEQ - 1) s_hi = T_SEQ - 1;

    for (int s0 = s_lo; s0 <= s_hi; s0 += 32) {
        f32x4 S[2];
#pragma unroll
        for (int sh = 0; sh < 2; sh++) {
            int srow = s0 + sh * 16 + c;          // in [0,T) by construction
            bf16x8 kf0 = *(const bf16x8*)(Kr + hb + (size_t)srow * 64 + g * 8);
            bf16x8 kf1 = *(const bf16x8*)(Kr + hb + (size_t)srow * 64 + 32 + g * 8);
            f32x4 z;
#pragma unroll
            for (int r = 0; r < 4; r++) z[r] = 0.f;
            z = __builtin_amdgcn_mfma_f32_16x16x32_bf16(qf0, kf0, z, 0, 0, 0);
            z = __builtin_amdgcn_mfma_f32_16x16x32_bf16(qf1, kf1, z, 0, 0, 0);
            S[sh] = z;
        }
        float sv[2][4], rm[4];
#pragma unroll
        for (int r = 0; r < 4; r++) {
            int q = t0 + g * 4 + r;
            rm[r] = -1e30f;
#pragma unroll
            for (int sh = 0; sh < 2; sh++) {
                int s = s0 + sh * 16 + c;
                bool keep = (s - q >= -WIN) && (s - q <= WIN);
                float v = keep ? S[sh][r] * SCALE_LOG2E : -1e30f;
                sv[sh][r] = v;
                rm[r] = fmaxf(rm[r], v);
            }
        }
#pragma unroll
        for (int off = 1; off < 16; off <<= 1)
#pragma unroll
            for (int r = 0; r < 4; r++) rm[r] = fmaxf(rm[r], __shfl_xor(rm[r], off, 64));
        float alpha[4], rs[4];
#pragma unroll
        for (int r = 0; r < 4; r++) {
            float mn = fmaxf(m_r[r], rm[r]);
            alpha[r] = exp2f(m_r[r] - mn);
            m_r[r] = mn;
            rs[r] = 0.f;
        }
        ushort_t* pb = pbuf[wid];
#pragma unroll
        for (int sh = 0; sh < 2; sh++)
#pragma unroll
            for (int r = 0; r < 4; r++) {
                float p = (sv[sh][r] <= -1e29f) ? 0.f : exp2f(sv[sh][r] - m_r[r]);
                rs[r] += p;
                pb[(g * 4 + r) * 32 + sh * 16 + c] = f2bf(p);
            }
        __asm__ volatile("s_waitcnt lgkmcnt(0)" ::: "memory");
        bf16x8 pf = *(const bf16x8*)&pb[c * 32 + g * 8];   // P in A-layout
        __asm__ volatile("" ::: "memory");  // keep next iter's stores below this load
#pragma unroll
        for (int off = 1; off < 16; off <<= 1)
#pragma unroll
            for (int r = 0; r < 4; r++) rs[r] += __shfl_xor(rs[r], off, 64);
#pragma unroll
        for (int r = 0; r < 4; r++) l_r[r] = l_r[r] * alpha[r] + rs[r];
#pragma unroll
        for (int di = 0; di < 4; di++)
#pragma unroll
            for (int r = 0; r < 4; r++) o[di][r] *= alpha[r];

        int sb = s0 + g * 8;
#pragma unroll
        for (int di = 0; di < 4; di++) {
            bf16x8 vf = *(const bf16x8*)(Vt + ((size_t)(n * NH + h) * 64 + di * 16 + c) * T_SEQ + sb);
            o[di] = __builtin_amdgcn_mfma_f32_16x16x32_bf16(pf, vf, o[di], 0, 0, 0);
        }
    }

#pragma unroll
    for (int di = 0; di < 4; di++)
#pragma unroll
        for (int r = 0; r < 4; r++) {
            int q = t0 + g * 4 + r;
            float val = o[di][r] / l_r[r];
            O[((size_t)(n * T_SEQ + q)) * DM + h * 64 + di * 16 + c] = f2bf(sane(val, 1e6f));
        }
}

// ---------------------------------------------------------------------------
extern "C" void kernel_launch(void* const* d_in, const int* in_sizes, int n_in,
                              void* d_out, int out_size, void* d_ws, size_t ws_size,
                              hipStream_t stream) {
    const float* x    = (const float*)d_in[0];
    const float* Wqkv = (const float*)d_in[1];
    const float* Wout = (const float*)d_in[2];
    const float* bout = (const float*)d_in[3];
    float* out = (float*)d_out;

    // Workspace (all bf16), peak 72 MB:
    //   0  .. 6  MB : WqkvT [3072][1024]
    //   6  .. 8  MB : WoutT [1024][1024]
    //   8  .. 24 MB : Qr [n][h][t][64]
    //   24 .. 40 MB : Kr
    //   40 .. 56 MB : Vr  (dead after vtrans; reused as Oat)
    //   56 .. 72 MB : xb [8192][1024] bf16  (dead after gemm_qkv; reused as Vt)
    const size_t NEED = 72ull << 20;
    if (ws_size < NEED) {
        kzero_f<<<dim3(8192), 256, 0, stream>>>(out);  // signature: absmax==ref
        return;
    }
    char* ws = (char*)d_ws;
    ushort_t* WqkvT = (ushort_t*)(ws);
    ushort_t* WoutT = (ushort_t*)(ws + (6ull << 20));
    ushort_t* Qr    = (ushort_t*)(ws + (8ull << 20));
    ushort_t* Kr    = (ushort_t*)(ws + (24ull << 20));
    ushort_t* Vr    = (ushort_t*)(ws + (40ull << 20));
    ushort_t* xb    = (ushort_t*)(ws + (56ull << 20));
    ushort_t* Vt    = xb;   // alias: xb dead once gemm_qkv finishes
    ushort_t* Oat   = Vr;   // alias: Vr dead after vtrans

    xcvt<<<dim3(4096), 256, 0, stream>>>(x, xb);
    ktranspose_f2b<<<dim3(48, 16), 256, 0, stream>>>(Wqkv, WqkvT, 1024, 3072);
    ktranspose_f2b<<<dim3(16, 16), 256, 0, stream>>>(Wout, WoutT, 1024, 1024);
    gemm_qkv<<<dim3(64, 24), 256, 0, stream>>>(xb, WqkvT, Qr, Kr, Vr);
    vtrans<<<dim3(32, 64), 256, 0, stream>>>(Vr, Vt);
    attn_swin<<<dim3(2048), 256, 0, stream>>>(Qr, Kr, Vt, Oat);
    gemm_out<<<dim3(64, 8), 256, 0, stream>>>(Oat, WoutT, out, bout);
}

// Round 7
// 255.278 us; speedup vs baseline: 1.2295x; 1.1102x over previous
//
#include <hip/hip_runtime.h>
#include <hip/hip_bf16.h>
#include <cstdint>
#include <cstddef>

typedef __bf16 bf16_t;
typedef bf16_t bf16x8 __attribute__((ext_vector_type(8)));
typedef float f32x4 __attribute__((ext_vector_type(4)));
typedef unsigned short ushort_t;

#define T_SEQ 2048
#define DM 1024
#define NH 16
#define HD 64
#define WIN 128
// ln(10000)/32
#define ROPE_C 0.28782313662425572f
// (1/sqrt(64)) * log2(e) -- attention softmax in log2 domain
#define SCALE_LOG2E 0.18033688011112042f
// fixed softmax shift (log2 domain): scores*scale*log2e ~ N(0,1.44^2), max ~8;
// softmax is shift-invariant, fp32 overflows only past 2^127 -- unreachable.
#define ATT_M 16.0f

__device__ __forceinline__ ushort_t f2bf(float f) {
    union { float f; unsigned u; } v; v.f = f;
    unsigned r = v.u + 0x7fff + ((v.u >> 16) & 1);
    return (ushort_t)(r >> 16);
}
__device__ __forceinline__ float sane(float v, float sent) {
    return (fabsf(v) < 1e30f) ? v : sent;
}
// Async global->LDS, 16 B per lane. LDS dest = wave-uniform base + lane*16.
__device__ __forceinline__ void gld16(const ushort_t* g, ushort_t* l) {
    __builtin_amdgcn_global_load_lds(
        (const __attribute__((address_space(1))) unsigned int*)g,
        (__attribute__((address_space(3))) unsigned int*)l, 16, 0, 0);
}

// ---------------------------------------------------------------------------
__global__ __launch_bounds__(256) void kzero_f(float* __restrict__ p) {
    size_t i = ((size_t)blockIdx.x * 256 + threadIdx.x) * 4;
    float4 z; z.x = z.y = z.z = z.w = 0.f;
    *(float4*)(p + i) = z;
}

// ---------------------------------------------------------------------------
// x fp32 -> bf16, flat copy. 8 elems/thread.
// ---------------------------------------------------------------------------
__global__ __launch_bounds__(256) void xcvt(const float* __restrict__ in,
                                            ushort_t* __restrict__ out) {
    size_t i = ((size_t)blockIdx.x * 256 + threadIdx.x) * 8;
    float4 a0 = *(const float4*)(in + i);
    float4 a1 = *(const float4*)(in + i + 4);
    ushort_t cv[8];
    cv[0] = f2bf(a0.x); cv[1] = f2bf(a0.y); cv[2] = f2bf(a0.z); cv[3] = f2bf(a0.w);
    cv[4] = f2bf(a1.x); cv[5] = f2bf(a1.y); cv[6] = f2bf(a1.z); cv[7] = f2bf(a1.w);
    *(uint4*)(out + i) = *(uint4*)cv;
}

// ---------------------------------------------------------------------------
// fp32 -> bf16 transpose: in[R][C] (float) -> out[C][R] (bf16). 64x64 tiles.
// ---------------------------------------------------------------------------
__global__ __launch_bounds__(256) void ktranspose_f2b(const float* __restrict__ in,
                                                      ushort_t* __restrict__ out,
                                                      int R, int C) {
    __shared__ __align__(16) ushort_t tile[64][72];
    const int c0 = blockIdx.x * 64, r0 = blockIdx.y * 64;
    const int tid = threadIdx.x;
    const int rl = tid >> 2, q4 = tid & 3;
    const float* src = in + (size_t)(r0 + rl) * C + c0 + q4 * 16;
    ushort_t cv[16];
#pragma unroll
    for (int i = 0; i < 4; i++) {
        float4 f = *(const float4*)(src + i * 4);
        cv[i * 4 + 0] = f2bf(f.x); cv[i * 4 + 1] = f2bf(f.y);
        cv[i * 4 + 2] = f2bf(f.z); cv[i * 4 + 3] = f2bf(f.w);
    }
    *(uint4*)&tile[rl][q4 * 16]     = *(uint4*)&cv[0];
    *(uint4*)&tile[rl][q4 * 16 + 8] = *(uint4*)&cv[8];
    __syncthreads();
    const int cl = tid >> 2;
    ushort_t tmp[16];
#pragma unroll
    for (int i = 0; i < 16; i++) tmp[i] = tile[q4 * 16 + i][cl];
    ushort_t* dst = out + (size_t)(c0 + cl) * R + r0 + q4 * 16;
    *(uint4*)(dst)     = *(uint4*)&tmp[0];
    *(uint4*)(dst + 8) = *(uint4*)&tmp[8];
}

// ---------------------------------------------------------------------------
// GEMM1 (m97 structure): qkv = xb[8192][1024] * WqkvT[3072][1024]^T with
// fused RoPE + head split. Q,K roped -> Qr/Kr [nh][t][64]; V written
// DIRECTLY TRANSPOSED -> Vt [nh][64][T] (saves the vtrans pass).
// ---------------------------------------------------------------------------
__global__ __launch_bounds__(256) void gemm_qkv(const ushort_t* __restrict__ A,
                                                const ushort_t* __restrict__ Bt,
                                                ushort_t* __restrict__ Qr,
                                                ushort_t* __restrict__ Kr,
                                                ushort_t* __restrict__ Vt) {
    __shared__ __align__(16) ushort_t As[128 * 32];
    __shared__ __align__(16) ushort_t Bs[128 * 32];
    const int m0 = blockIdx.x * 128, n0 = blockIdx.y * 128;
    const int tid = threadIdx.x;
    const int lane = tid & 63, w = tid >> 6;
    const int wm = (w & 1) * 64, wn = (w >> 1) * 64;
    const int c = lane & 15, g = lane >> 4;
    const int lrow = lane >> 2, lcol = (lane & 3) * 8;   // staging lane map
    const int ch0 = 2 * w, ch1 = 2 * w + 1;

    f32x4 acc[4][4];
#pragma unroll
    for (int mi = 0; mi < 4; mi++)
#pragma unroll
        for (int ni = 0; ni < 4; ni++)
#pragma unroll
            for (int r = 0; r < 4; r++) acc[mi][ni][r] = 0.f;

    for (int k0 = 0; k0 < 1024; k0 += 32) {
        __syncthreads();
        gld16(A  + (size_t)(m0 + ch0 * 16 + lrow) * 1024 + k0 + lcol, &As[ch0 * 512]);
        gld16(A  + (size_t)(m0 + ch1 * 16 + lrow) * 1024 + k0 + lcol, &As[ch1 * 512]);
        gld16(Bt + (size_t)(n0 + ch0 * 16 + lrow) * 1024 + k0 + lcol, &Bs[ch0 * 512]);
        gld16(Bt + (size_t)(n0 + ch1 * 16 + lrow) * 1024 + k0 + lcol, &Bs[ch1 * 512]);
        __syncthreads();
        bf16x8 af[4], bfr[4];
#pragma unroll
        for (int mi = 0; mi < 4; mi++)
            af[mi] = *(const bf16x8*)&As[(wm + mi * 16 + c) * 32 + g * 8];
#pragma unroll
        for (int ni = 0; ni < 4; ni++)
            bfr[ni] = *(const bf16x8*)&Bs[(wn + ni * 16 + c) * 32 + g * 8];
#pragma unroll
        for (int mi = 0; mi < 4; mi++)
#pragma unroll
            for (int ni = 0; ni < 4; ni++)
                acc[mi][ni] = __builtin_amdgcn_mfma_f32_16x16x32_bf16(
                    af[mi], bfr[ni], acc[mi][ni], 0, 0, 0);
    }

    const int nb = n0 + wn;             // 64-aligned wave column base
    const int sec = nb >> 10;           // 0=Q 1=K 2=V
    const int h = (nb >> 6) & 15;

    if (sec < 2) {
        ushort_t* dst = (sec == 0) ? Qr : Kr;
        const float invf0 = __expf(-(float)(c) * ROPE_C);        // pair i = c
        const float invf1 = __expf(-(float)(16 + c) * ROPE_C);   // pair i = 16+c
#pragma unroll
        for (int mi = 0; mi < 4; mi++)
#pragma unroll
            for (int r = 0; r < 4; r++) {
                int tg = m0 + wm + mi * 16 + g * 4 + r;
                int nB = tg >> 11, t = tg & (T_SEQ - 1);
                // native v_sin/v_cos: arg error <= 2.4e-4 rad at t<=2048 (OK)
                float a0 = (float)t * invf0, a1 = (float)t * invf1;
                float s0 = __sinf(a0), c0 = __cosf(a0);
                float s1 = __sinf(a1), c1 = __cosf(a1);
                size_t base = ((size_t)(nB * NH + h) * T_SEQ + t) * 64;
                float x1a = acc[mi][0][r], x2a = acc[mi][2][r];
                float x1b = acc[mi][1][r], x2b = acc[mi][3][r];
                dst[base + c]      = f2bf(sane(x1a * c0 - x2a * s0, 1e3f));
                dst[base + 16 + c] = f2bf(sane(x1b * c1 - x2b * s1, 1e3f));
                dst[base + 32 + c] = f2bf(sane(x1a * s0 + x2a * c0, 1e3f));
                dst[base + 48 + c] = f2bf(sane(x1b * s1 + x2b * c1, 1e3f));
            }
    } else {
        // V: write directly transposed into Vt[nh][64][T]
#pragma unroll
        for (int mi = 0; mi < 4; mi++)
#pragma unroll
            for (int r = 0; r < 4; r++) {
                int tg = m0 + wm + mi * 16 + g * 4 + r;
                int nB = tg >> 11, t = tg & (T_SEQ - 1);
                size_t vbase = (size_t)(nB * NH + h) * 64 * T_SEQ + t;
#pragma unroll
                for (int ni = 0; ni < 4; ni++)
                    Vt[vbase + (size_t)(ni * 16 + c) * T_SEQ] =
                        f2bf(sane(acc[mi][ni][r], 1e3f));
            }
    }
}

// ---------------------------------------------------------------------------
// Final projection (m97 structure): C[M][1024] fp32 = A bf16 * WoutT^T + bias.
// ---------------------------------------------------------------------------
__global__ __launch_bounds__(256) void gemm_out(const ushort_t* __restrict__ A,
                                                const ushort_t* __restrict__ Bt,
                                                float* __restrict__ C,
                                                const float* __restrict__ bias) {
    __shared__ __align__(16) ushort_t As[128 * 32];
    __shared__ __align__(16) ushort_t Bs[128 * 32];
    const int m0 = blockIdx.x * 128, n0 = blockIdx.y * 128;
    const int tid = threadIdx.x;
    const int lane = tid & 63, w = tid >> 6;
    const int wm = (w & 1) * 64, wn = (w >> 1) * 64;
    const int c = lane & 15, g = lane >> 4;
    const int lrow = lane >> 2, lcol = (lane & 3) * 8;
    const int ch0 = 2 * w, ch1 = 2 * w + 1;

    f32x4 acc[4][4];
#pragma unroll
    for (int mi = 0; mi < 4; mi++)
#pragma unroll
        for (int ni = 0; ni < 4; ni++)
#pragma unroll
            for (int r = 0; r < 4; r++) acc[mi][ni][r] = 0.f;

    for (int k0 = 0; k0 < 1024; k0 += 32) {
        __syncthreads();
        gld16(A  + (size_t)(m0 + ch0 * 16 + lrow) * 1024 + k0 + lcol, &As[ch0 * 512]);
        gld16(A  + (size_t)(m0 + ch1 * 16 + lrow) * 1024 + k0 + lcol, &As[ch1 * 512]);
        gld16(Bt + (size_t)(n0 + ch0 * 16 + lrow) * 1024 + k0 + lcol, &Bs[ch0 * 512]);
        gld16(Bt + (size_t)(n0 + ch1 * 16 + lrow) * 1024 + k0 + lcol, &Bs[ch1 * 512]);
        __syncthreads();
        bf16x8 af[4], bfr[4];
#pragma unroll
        for (int mi = 0; mi < 4; mi++)
            af[mi] = *(const bf16x8*)&As[(wm + mi * 16 + c) * 32 + g * 8];
#pragma unroll
        for (int ni = 0; ni < 4; ni++)
            bfr[ni] = *(const bf16x8*)&Bs[(wn + ni * 16 + c) * 32 + g * 8];
#pragma unroll
        for (int mi = 0; mi < 4; mi++)
#pragma unroll
            for (int ni = 0; ni < 4; ni++)
                acc[mi][ni] = __builtin_amdgcn_mfma_f32_16x16x32_bf16(
                    af[mi], bfr[ni], acc[mi][ni], 0, 0, 0);
    }

#pragma unroll
    for (int ni = 0; ni < 4; ni++) {
        int col = n0 + wn + ni * 16 + c;
        float bv = bias[col];
#pragma unroll
        for (int mi = 0; mi < 4; mi++)
#pragma unroll
            for (int r = 0; r < 4; r++) {
                int rowi = m0 + wm + mi * 16 + g * 4 + r;
                C[(size_t)rowi * 1024 + col] = sane(acc[mi][ni][r] + bv, 1e8f);
            }
    }
}

// ---------------------------------------------------------------------------
// Sliding-window flash attention, FIXED-MAX softmax (no online max/rescale):
// p = 2^(score*scale*log2e - 16); row-sum accumulated lane-locally, reduced
// once at the end. Wave-uniform `interior` skips masking on inner tiles.
// Per-wave LDS P round-trip with lgkmcnt fence (trip counts differ per wave
// -> __syncthreads illegal).
// ---------------------------------------------------------------------------
__global__ __launch_bounds__(256) void attn_swin(const ushort_t* __restrict__ Qr,
                                                 const ushort_t* __restrict__ Kr,
                                                 const ushort_t* __restrict__ Vt,
                                                 ushort_t* __restrict__ O) {
    __shared__ __align__(16) ushort_t pbuf[4][16 * 32];
    const int wid = threadIdx.x >> 6, lane = threadIdx.x & 63;
    const int gid = blockIdx.x * 4 + wid;
    const int qt = gid & 127, h = (gid >> 7) & 15, n = gid >> 11;
    const int t0 = qt * 16;
    const int c = lane & 15, g = lane >> 4;
    const size_t hb = ((size_t)(n * NH + h)) * T_SEQ * 64;

    bf16x8 qf0 = *(const bf16x8*)(Qr + hb + (size_t)(t0 + c) * 64 + g * 8);
    bf16x8 qf1 = *(const bf16x8*)(Qr + hb + (size_t)(t0 + c) * 64 + 32 + g * 8);

    f32x4 o[4];
    float l_r[4];
#pragma unroll
    for (int i = 0; i < 4; i++) {
        l_r[i] = 0.f;
#pragma unroll
        for (int r = 0; r < 4; r++) o[i][r] = 0.f;
    }

    int s_lo = (t0 - WIN) & ~31; if (s_lo < 0) s_lo = 0;
    int s_hi = t0 + 15 + WIN;    if (s_hi > T_SEQ - 1) s_hi = T_SEQ - 1;

    for (int s0 = s_lo; s0 <= s_hi; s0 += 32) {
        f32x4 S[2];
#pragma unroll
        for (int sh = 0; sh < 2; sh++) {
            int srow = s0 + sh * 16 + c;          // in [0,T) by construction
            bf16x8 kf0 = *(const bf16x8*)(Kr + hb + (size_t)srow * 64 + g * 8);
            bf16x8 kf1 = *(const bf16x8*)(Kr + hb + (size_t)srow * 64 + 32 + g * 8);
            f32x4 z;
#pragma unroll
            for (int r = 0; r < 4; r++) z[r] = 0.f;
            z = __builtin_amdgcn_mfma_f32_16x16x32_bf16(qf0, kf0, z, 0, 0, 0);
            z = __builtin_amdgcn_mfma_f32_16x16x32_bf16(qf1, kf1, z, 0, 0, 0);
            S[sh] = z;
        }
        // wave-uniform: tile fully inside window for all 16 queries?
        const bool interior = (s0 >= t0 - 113) && (s0 <= t0 + 97);
        ushort_t* pb = pbuf[wid];
        if (interior) {
#pragma unroll
            for (int sh = 0; sh < 2; sh++)
#pragma unroll
                for (int r = 0; r < 4; r++) {
                    float p = exp2f(S[sh][r] * SCALE_LOG2E - ATT_M);
                    l_r[r] += p;
                    pb[(g * 4 + r) * 32 + sh * 16 + c] = f2bf(p);
                }
        } else {
#pragma unroll
            for (int sh = 0; sh < 2; sh++)
#pragma unroll
                for (int r = 0; r < 4; r++) {
                    int s = s0 + sh * 16 + c;
                    int q = t0 + g * 4 + r;
                    bool keep = (s - q >= -WIN) && (s - q <= WIN);
                    float v = keep ? S[sh][r] * SCALE_LOG2E : -1e30f;
                    float p = exp2f(v - ATT_M);     // masked -> exp2(-inf)=0
                    l_r[r] += p;
                    pb[(g * 4 + r) * 32 + sh * 16 + c] = f2bf(p);
                }
        }
        __asm__ volatile("s_waitcnt lgkmcnt(0)" ::: "memory");
        bf16x8 pf = *(const bf16x8*)&pb[c * 32 + g * 8];   // P in A-layout
        __asm__ volatile("" ::: "memory");  // keep next iter's stores below this load

        int sb = s0 + g * 8;
#pragma unroll
        for (int di = 0; di < 4; di++) {
            bf16x8 vf = *(const bf16x8*)(Vt + ((size_t)(n * NH + h) * 64 + di * 16 + c) * T_SEQ + sb);
            o[di] = __builtin_amdgcn_mfma_f32_16x16x32_bf16(pf, vf, o[di], 0, 0, 0);
        }
    }

    // single end-of-loop row-sum reduce across the 16 c-lanes
#pragma unroll
    for (int off = 1; off < 16; off <<= 1)
#pragma unroll
        for (int r = 0; r < 4; r++) l_r[r] += __shfl_xor(l_r[r], off, 64);
    float inv[4];
#pragma unroll
    for (int r = 0; r < 4; r++) inv[r] = __builtin_amdgcn_rcpf(l_r[r]);

#pragma unroll
    for (int di = 0; di < 4; di++)
#pragma unroll
        for (int r = 0; r < 4; r++) {
            int q = t0 + g * 4 + r;
            float val = o[di][r] * inv[r];
            O[((size_t)(n * T_SEQ + q)) * DM + h * 64 + di * 16 + c] = f2bf(sane(val, 1e6f));
        }
}

// ---------------------------------------------------------------------------
extern "C" void kernel_launch(void* const* d_in, const int* in_sizes, int n_in,
                              void* d_out, int out_size, void* d_ws, size_t ws_size,
                              hipStream_t stream) {
    const float* x    = (const float*)d_in[0];
    const float* Wqkv = (const float*)d_in[1];
    const float* Wout = (const float*)d_in[2];
    const float* bout = (const float*)d_in[3];
    float* out = (float*)d_out;

    // Workspace (all bf16), peak 72 MB:
    //   0  .. 6  MB : WqkvT [3072][1024]
    //   6  .. 8  MB : WoutT [1024][1024]
    //   8  .. 24 MB : Qr [nh][t][64]
    //   24 .. 40 MB : Kr
    //   40 .. 56 MB : Vt [nh][64][T]   (written directly by gemm_qkv)
    //   56 .. 72 MB : xb [8192][1024]  (dead after gemm_qkv; reused as Oat)
    const size_t NEED = 72ull << 20;
    if (ws_size < NEED) {
        kzero_f<<<dim3(8192), 256, 0, stream>>>(out);  // signature: absmax==ref
        return;
    }
    char* ws = (char*)d_ws;
    ushort_t* WqkvT = (ushort_t*)(ws);
    ushort_t* WoutT = (ushort_t*)(ws + (6ull << 20));
    ushort_t* Qr    = (ushort_t*)(ws + (8ull << 20));
    ushort_t* Kr    = (ushort_t*)(ws + (24ull << 20));
    ushort_t* Vt    = (ushort_t*)(ws + (40ull << 20));
    ushort_t* xb    = (ushort_t*)(ws + (56ull << 20));
    ushort_t* Oat   = xb;   // alias: xb dead once gemm_qkv finishes

    xcvt<<<dim3(4096), 256, 0, stream>>>(x, xb);
    ktranspose_f2b<<<dim3(48, 16), 256, 0, stream>>>(Wqkv, WqkvT, 1024, 3072);
    ktranspose_f2b<<<dim3(16, 16), 256, 0, stream>>>(Wout, WoutT, 1024, 1024);
    gemm_qkv<<<dim3(64, 24), 256, 0, stream>>>(xb, WqkvT, Qr, Kr, Vt);
    attn_swin<<<dim3(2048), 256, 0, stream>>>(Qr, Kr, Vt, Oat);
    gemm_out<<<dim3(64, 8), 256, 0, stream>>>(Oat, WoutT, out, bout);
}

// Round 8
// 223.225 us; speedup vs baseline: 1.4060x; 1.1436x over previous
//
#include <hip/hip_runtime.h>
#include <hip/hip_bf16.h>
#include <cstdint>
#include <cstddef>

typedef __bf16 bf16_t;
typedef bf16_t bf16x8 __attribute__((ext_vector_type(8)));
typedef float f32x4 __attribute__((ext_vector_type(4)));
typedef unsigned short ushort_t;

#define T_SEQ 2048
#define DM 1024
#define NH 16
#define HD 64
#define WIN 128
// ln(10000)/32
#define ROPE_C 0.28782313662425572f
// (1/sqrt(64)) * log2(e) -- attention softmax in log2 domain
#define SCALE_LOG2E 0.18033688011112042f
// fixed softmax shift (log2 domain); softmax is shift-invariant
#define ATT_M 16.0f

__device__ __forceinline__ ushort_t f2bf(float f) {
    union { float f; unsigned u; } v; v.f = f;
    unsigned r = v.u + 0x7fff + ((v.u >> 16) & 1);
    return (ushort_t)(r >> 16);
}
__device__ __forceinline__ float sane(float v, float sent) {
    return (fabsf(v) < 1e30f) ? v : sent;
}
// Async global->LDS, 16 B per lane. LDS dest = wave-uniform base + lane*16.
__device__ __forceinline__ void gld16(const ushort_t* g, ushort_t* l) {
    __builtin_amdgcn_global_load_lds(
        (const __attribute__((address_space(1))) unsigned int*)g,
        (__attribute__((address_space(3))) unsigned int*)l, 16, 0, 0);
}

// ---------------------------------------------------------------------------
__global__ __launch_bounds__(256) void kzero_f(float* __restrict__ p) {
    size_t i = ((size_t)blockIdx.x * 256 + threadIdx.x) * 4;
    float4 z; z.x = z.y = z.z = z.w = 0.f;
    *(float4*)(p + i) = z;
}

// ---------------------------------------------------------------------------
// x fp32 -> bf16, flat copy. 8 elems/thread.
// ---------------------------------------------------------------------------
__global__ __launch_bounds__(256) void xcvt(const float* __restrict__ in,
                                            ushort_t* __restrict__ out) {
    size_t i = ((size_t)blockIdx.x * 256 + threadIdx.x) * 8;
    float4 a0 = *(const float4*)(in + i);
    float4 a1 = *(const float4*)(in + i + 4);
    ushort_t cv[8];
    cv[0] = f2bf(a0.x); cv[1] = f2bf(a0.y); cv[2] = f2bf(a0.z); cv[3] = f2bf(a0.w);
    cv[4] = f2bf(a1.x); cv[5] = f2bf(a1.y); cv[6] = f2bf(a1.z); cv[7] = f2bf(a1.w);
    *(uint4*)(out + i) = *(uint4*)cv;
}

// ---------------------------------------------------------------------------
// fp32 -> bf16 transpose: in[R][C] (float) -> out[C][R] (bf16). 64x64 tiles.
// ---------------------------------------------------------------------------
__global__ __launch_bounds__(256) void ktranspose_f2b(const float* __restrict__ in,
                                                      ushort_t* __restrict__ out,
                                                      int R, int C) {
    __shared__ __align__(16) ushort_t tile[64][72];
    const int c0 = blockIdx.x * 64, r0 = blockIdx.y * 64;
    const int tid = threadIdx.x;
    const int rl = tid >> 2, q4 = tid & 3;
    const float* src = in + (size_t)(r0 + rl) * C + c0 + q4 * 16;
    ushort_t cv[16];
#pragma unroll
    for (int i = 0; i < 4; i++) {
        float4 f = *(const float4*)(src + i * 4);
        cv[i * 4 + 0] = f2bf(f.x); cv[i * 4 + 1] = f2bf(f.y);
        cv[i * 4 + 2] = f2bf(f.z); cv[i * 4 + 3] = f2bf(f.w);
    }
    *(uint4*)&tile[rl][q4 * 16]     = *(uint4*)&cv[0];
    *(uint4*)&tile[rl][q4 * 16 + 8] = *(uint4*)&cv[8];
    __syncthreads();
    const int cl = tid >> 2;
    ushort_t tmp[16];
#pragma unroll
    for (int i = 0; i < 16; i++) tmp[i] = tile[q4 * 16 + i][cl];
    ushort_t* dst = out + (size_t)(c0 + cl) * R + r0 + q4 * 16;
    *(uint4*)(dst)     = *(uint4*)&tmp[0];
    *(uint4*)(dst + 8) = *(uint4*)&tmp[8];
}

// ---------------------------------------------------------------------------
// GEMM1 (m97 structure): qkv = xb[8192][1024] * WqkvT[3072][1024]^T with
// fused RoPE + head split. Q,K roped -> Qr/Kr [nh][t][64]; V written
// directly transposed -> Vt [nh][64][T] (8B-vectorized along t).
// ---------------------------------------------------------------------------
__global__ __launch_bounds__(256) void gemm_qkv(const ushort_t* __restrict__ A,
                                                const ushort_t* __restrict__ Bt,
                                                ushort_t* __restrict__ Qr,
                                                ushort_t* __restrict__ Kr,
                                                ushort_t* __restrict__ Vt) {
    __shared__ __align__(16) ushort_t As[128 * 32];
    __shared__ __align__(16) ushort_t Bs[128 * 32];
    const int m0 = blockIdx.x * 128, n0 = blockIdx.y * 128;
    const int tid = threadIdx.x;
    const int lane = tid & 63, w = tid >> 6;
    const int wm = (w & 1) * 64, wn = (w >> 1) * 64;
    const int c = lane & 15, g = lane >> 4;
    const int lrow = lane >> 2, lcol = (lane & 3) * 8;   // staging lane map
    const int ch0 = 2 * w, ch1 = 2 * w + 1;

    f32x4 acc[4][4];
#pragma unroll
    for (int mi = 0; mi < 4; mi++)
#pragma unroll
        for (int ni = 0; ni < 4; ni++)
#pragma unroll
            for (int r = 0; r < 4; r++) acc[mi][ni][r] = 0.f;

    for (int k0 = 0; k0 < 1024; k0 += 32) {
        __syncthreads();
        gld16(A  + (size_t)(m0 + ch0 * 16 + lrow) * 1024 + k0 + lcol, &As[ch0 * 512]);
        gld16(A  + (size_t)(m0 + ch1 * 16 + lrow) * 1024 + k0 + lcol, &As[ch1 * 512]);
        gld16(Bt + (size_t)(n0 + ch0 * 16 + lrow) * 1024 + k0 + lcol, &Bs[ch0 * 512]);
        gld16(Bt + (size_t)(n0 + ch1 * 16 + lrow) * 1024 + k0 + lcol, &Bs[ch1 * 512]);
        __syncthreads();
        bf16x8 af[4], bfr[4];
#pragma unroll
        for (int mi = 0; mi < 4; mi++)
            af[mi] = *(const bf16x8*)&As[(wm + mi * 16 + c) * 32 + g * 8];
#pragma unroll
        for (int ni = 0; ni < 4; ni++)
            bfr[ni] = *(const bf16x8*)&Bs[(wn + ni * 16 + c) * 32 + g * 8];
#pragma unroll
        for (int mi = 0; mi < 4; mi++)
#pragma unroll
            for (int ni = 0; ni < 4; ni++)
                acc[mi][ni] = __builtin_amdgcn_mfma_f32_16x16x32_bf16(
                    af[mi], bfr[ni], acc[mi][ni], 0, 0, 0);
    }

    const int nb = n0 + wn;             // 64-aligned wave column base
    const int sec = nb >> 10;           // 0=Q 1=K 2=V
    const int h = (nb >> 6) & 15;

    if (sec < 2) {
        ushort_t* dst = (sec == 0) ? Qr : Kr;
        const float invf0 = __expf(-(float)(c) * ROPE_C);        // pair i = c
        const float invf1 = __expf(-(float)(16 + c) * ROPE_C);   // pair i = 16+c
#pragma unroll
        for (int mi = 0; mi < 4; mi++)
#pragma unroll
            for (int r = 0; r < 4; r++) {
                int tg = m0 + wm + mi * 16 + g * 4 + r;
                int nB = tg >> 11, t = tg & (T_SEQ - 1);
                float a0 = (float)t * invf0, a1 = (float)t * invf1;
                float s0 = __sinf(a0), c0 = __cosf(a0);
                float s1 = __sinf(a1), c1 = __cosf(a1);
                size_t base = ((size_t)(nB * NH + h) * T_SEQ + t) * 64;
                float x1a = acc[mi][0][r], x2a = acc[mi][2][r];
                float x1b = acc[mi][1][r], x2b = acc[mi][3][r];
                dst[base + c]      = f2bf(sane(x1a * c0 - x2a * s0, 1e3f));
                dst[base + 16 + c] = f2bf(sane(x1b * c1 - x2b * s1, 1e3f));
                dst[base + 32 + c] = f2bf(sane(x1a * s0 + x2a * c0, 1e3f));
                dst[base + 48 + c] = f2bf(sane(x1b * s1 + x2b * c1, 1e3f));
            }
    } else {
        // V: write transposed into Vt[nh][64][T]; 4 consecutive t per store
#pragma unroll
        for (int mi = 0; mi < 4; mi++) {
            int tgb = m0 + wm + mi * 16 + g * 4;
            int nB = tgb >> 11, t = tgb & (T_SEQ - 1);
            size_t vrow = (size_t)(nB * NH + h) * 64 * T_SEQ;
#pragma unroll
            for (int ni = 0; ni < 4; ni++) {
                ushort4 pk;
                pk.x = f2bf(sane(acc[mi][ni][0], 1e3f));
                pk.y = f2bf(sane(acc[mi][ni][1], 1e3f));
                pk.z = f2bf(sane(acc[mi][ni][2], 1e3f));
                pk.w = f2bf(sane(acc[mi][ni][3], 1e3f));
                *(ushort4*)&Vt[vrow + (size_t)(ni * 16 + c) * T_SEQ + t] = pk;
            }
        }
    }
}

// ---------------------------------------------------------------------------
// Final projection (m97 structure): C[M][1024] fp32 = A bf16 * WoutT^T + bias.
// ---------------------------------------------------------------------------
__global__ __launch_bounds__(256) void gemm_out(const ushort_t* __restrict__ A,
                                                const ushort_t* __restrict__ Bt,
                                                float* __restrict__ C,
                                                const float* __restrict__ bias) {
    __shared__ __align__(16) ushort_t As[128 * 32];
    __shared__ __align__(16) ushort_t Bs[128 * 32];
    const int m0 = blockIdx.x * 128, n0 = blockIdx.y * 128;
    const int tid = threadIdx.x;
    const int lane = tid & 63, w = tid >> 6;
    const int wm = (w & 1) * 64, wn = (w >> 1) * 64;
    const int c = lane & 15, g = lane >> 4;
    const int lrow = lane >> 2, lcol = (lane & 3) * 8;
    const int ch0 = 2 * w, ch1 = 2 * w + 1;

    f32x4 acc[4][4];
#pragma unroll
    for (int mi = 0; mi < 4; mi++)
#pragma unroll
        for (int ni = 0; ni < 4; ni++)
#pragma unroll
            for (int r = 0; r < 4; r++) acc[mi][ni][r] = 0.f;

    for (int k0 = 0; k0 < 1024; k0 += 32) {
        __syncthreads();
        gld16(A  + (size_t)(m0 + ch0 * 16 + lrow) * 1024 + k0 + lcol, &As[ch0 * 512]);
        gld16(A  + (size_t)(m0 + ch1 * 16 + lrow) * 1024 + k0 + lcol, &As[ch1 * 512]);
        gld16(Bt + (size_t)(n0 + ch0 * 16 + lrow) * 1024 + k0 + lcol, &Bs[ch0 * 512]);
        gld16(Bt + (size_t)(n0 + ch1 * 16 + lrow) * 1024 + k0 + lcol, &Bs[ch1 * 512]);
        __syncthreads();
        bf16x8 af[4], bfr[4];
#pragma unroll
        for (int mi = 0; mi < 4; mi++)
            af[mi] = *(const bf16x8*)&As[(wm + mi * 16 + c) * 32 + g * 8];
#pragma unroll
        for (int ni = 0; ni < 4; ni++)
            bfr[ni] = *(const bf16x8*)&Bs[(wn + ni * 16 + c) * 32 + g * 8];
#pragma unroll
        for (int mi = 0; mi < 4; mi++)
#pragma unroll
            for (int ni = 0; ni < 4; ni++)
                acc[mi][ni] = __builtin_amdgcn_mfma_f32_16x16x32_bf16(
                    af[mi], bfr[ni], acc[mi][ni], 0, 0, 0);
    }

#pragma unroll
    for (int ni = 0; ni < 4; ni++) {
        int col = n0 + wn + ni * 16 + c;
        float bv = bias[col];
#pragma unroll
        for (int mi = 0; mi < 4; mi++)
#pragma unroll
            for (int r = 0; r < 4; r++) {
                int rowi = m0 + wm + mi * 16 + g * 4 + r;
                C[(size_t)rowi * 1024 + col] = sane(acc[mi][ni][r] + bv, 1e8f);
            }
    }
}

// ---------------------------------------------------------------------------
// Cooperative sliding-window attention. Block = 4 waves = 64 queries of one
// (n,h); block-uniform s-tile loop -> __syncthreads legal. K tile (32x64) and
// V^T tile (64x32) staged in LDS (72-elem row stride: 2-way banks = free),
// register-prefetched one tile ahead. Fixed-max softmax (p=2^(s*scale-16)),
// lane-local row-sum, one reduce at the end. Per-wave pbuf round-trip keeps
// the lgkmcnt fence (cross-lane through LDS within a wave).
// ---------------------------------------------------------------------------
__global__ __launch_bounds__(256) void attn_swin(const ushort_t* __restrict__ Qr,
                                                 const ushort_t* __restrict__ Kr,
                                                 const ushort_t* __restrict__ Vt,
                                                 ushort_t* __restrict__ O) {
    __shared__ __align__(16) ushort_t Ks[32 * 72];
    __shared__ __align__(16) ushort_t Vs[64 * 72];
    __shared__ __align__(16) ushort_t pbuf[4][16 * 32];
    const int tid = threadIdx.x;
    const int wid = tid >> 6, lane = tid & 63;
    const int qb = (blockIdx.x & 31) * 64;
    const int h = (blockIdx.x >> 5) & 15, n = blockIdx.x >> 9;
    const int t0 = qb + wid * 16;
    const int c = lane & 15, g = lane >> 4;
    const size_t hb = ((size_t)(n * NH + h)) * T_SEQ * 64;
    // staging maps
    const int ks_row = tid >> 3, ks_col = (tid & 7) * 8;   // 32 rows x 64 el
    const int vs_row = tid >> 2, vs_col = (tid & 3) * 8;   // 64 rows x 32 el

    bf16x8 qf0 = *(const bf16x8*)(Qr + hb + (size_t)(t0 + c) * 64 + g * 8);
    bf16x8 qf1 = *(const bf16x8*)(Qr + hb + (size_t)(t0 + c) * 64 + 32 + g * 8);

    f32x4 o[4];
    float l_r[4];
#pragma unroll
    for (int i = 0; i < 4; i++) {
        l_r[i] = 0.f;
#pragma unroll
        for (int r = 0; r < 4; r++) o[i][r] = 0.f;
    }

    int sB_lo = qb - WIN;       if (sB_lo < 0) sB_lo = 0;
    int sB_hi = qb + 63 + WIN;  if (sB_hi > T_SEQ - 1) sB_hi = T_SEQ - 1;

    uint4 kreg = *(const uint4*)(Kr + hb + (size_t)(sB_lo + ks_row) * 64 + ks_col);
    uint4 vreg = *(const uint4*)(Vt + hb + (size_t)vs_row * T_SEQ + sB_lo + vs_col);

    for (int s0 = sB_lo; s0 <= sB_hi; s0 += 32) {
        __syncthreads();                       // LDS free (prev compute done)
        *(uint4*)&Ks[ks_row * 72 + ks_col] = kreg;
        *(uint4*)&Vs[vs_row * 72 + vs_col] = vreg;
        __syncthreads();                       // tile staged
        int s1 = s0 + 32;
        if (s1 <= sB_hi) {                     // prefetch next tile
            kreg = *(const uint4*)(Kr + hb + (size_t)(s1 + ks_row) * 64 + ks_col);
            vreg = *(const uint4*)(Vt + hb + (size_t)vs_row * T_SEQ + s1 + vs_col);
        }
        // wave-uniform: does this tile intersect this wave's window?
        if (s0 > t0 + 143 || s0 + 31 < t0 - WIN) continue;

        f32x4 S[2];
#pragma unroll
        for (int sh = 0; sh < 2; sh++) {
            bf16x8 kf0 = *(const bf16x8*)&Ks[(sh * 16 + c) * 72 + g * 8];
            bf16x8 kf1 = *(const bf16x8*)&Ks[(sh * 16 + c) * 72 + 32 + g * 8];
            f32x4 z;
#pragma unroll
            for (int r = 0; r < 4; r++) z[r] = 0.f;
            z = __builtin_amdgcn_mfma_f32_16x16x32_bf16(qf0, kf0, z, 0, 0, 0);
            z = __builtin_amdgcn_mfma_f32_16x16x32_bf16(qf1, kf1, z, 0, 0, 0);
            S[sh] = z;
        }
        const bool interior = (s0 >= t0 - 113) && (s0 <= t0 + 97);
        ushort_t* pb = pbuf[wid];
        if (interior) {
#pragma unroll
            for (int sh = 0; sh < 2; sh++)
#pragma unroll
                for (int r = 0; r < 4; r++) {
                    float p = exp2f(S[sh][r] * SCALE_LOG2E - ATT_M);
                    l_r[r] += p;
                    pb[(g * 4 + r) * 32 + sh * 16 + c] = f2bf(p);
                }
        } else {
#pragma unroll
            for (int sh = 0; sh < 2; sh++)
#pragma unroll
                for (int r = 0; r < 4; r++) {
                    int s = s0 + sh * 16 + c;
                    int q = t0 + g * 4 + r;
                    bool keep = (s - q >= -WIN) && (s - q <= WIN);
                    float v = keep ? S[sh][r] * SCALE_LOG2E : -1e30f;
                    float p = exp2f(v - ATT_M);     // masked -> 0
                    l_r[r] += p;
                    pb[(g * 4 + r) * 32 + sh * 16 + c] = f2bf(p);
                }
        }
        __asm__ volatile("s_waitcnt lgkmcnt(0)" ::: "memory");
        bf16x8 pf = *(const bf16x8*)&pb[c * 32 + g * 8];   // P in A-layout
        __asm__ volatile("" ::: "memory");

#pragma unroll
        for (int di = 0; di < 4; di++) {
            bf16x8 vf = *(const bf16x8*)&Vs[(di * 16 + c) * 72 + g * 8];
            o[di] = __builtin_amdgcn_mfma_f32_16x16x32_bf16(pf, vf, o[di], 0, 0, 0);
        }
    }

    // single end-of-loop row-sum reduce across the 16 c-lanes
#pragma unroll
    for (int off = 1; off < 16; off <<= 1)
#pragma unroll
        for (int r = 0; r < 4; r++) l_r[r] += __shfl_xor(l_r[r], off, 64);
    float inv[4];
#pragma unroll
    for (int r = 0; r < 4; r++) inv[r] = __builtin_amdgcn_rcpf(l_r[r]);

#pragma unroll
    for (int di = 0; di < 4; di++)
#pragma unroll
        for (int r = 0; r < 4; r++) {
            int q = t0 + g * 4 + r;
            float val = o[di][r] * inv[r];
            O[((size_t)(n * T_SEQ + q)) * DM + h * 64 + di * 16 + c] = f2bf(sane(val, 1e6f));
        }
}

// ---------------------------------------------------------------------------
extern "C" void kernel_launch(void* const* d_in, const int* in_sizes, int n_in,
                              void* d_out, int out_size, void* d_ws, size_t ws_size,
                              hipStream_t stream) {
    const float* x    = (const float*)d_in[0];
    const float* Wqkv = (const float*)d_in[1];
    const float* Wout = (const float*)d_in[2];
    const float* bout = (const float*)d_in[3];
    float* out = (float*)d_out;

    // Workspace (all bf16), peak 72 MB:
    //   0  .. 6  MB : WqkvT [3072][1024]
    //   6  .. 8  MB : WoutT [1024][1024]
    //   8  .. 24 MB : Qr [nh][t][64]
    //   24 .. 40 MB : Kr
    //   40 .. 56 MB : Vt [nh][64][T]   (written directly by gemm_qkv)
    //   56 .. 72 MB : xb [8192][1024]  (dead after gemm_qkv; reused as Oat)
    const size_t NEED = 72ull << 20;
    if (ws_size < NEED) {
        kzero_f<<<dim3(8192), 256, 0, stream>>>(out);  // signature: absmax==ref
        return;
    }
    char* ws = (char*)d_ws;
    ushort_t* WqkvT = (ushort_t*)(ws);
    ushort_t* WoutT = (ushort_t*)(ws + (6ull << 20));
    ushort_t* Qr    = (ushort_t*)(ws + (8ull << 20));
    ushort_t* Kr    = (ushort_t*)(ws + (24ull << 20));
    ushort_t* Vt    = (ushort_t*)(ws + (40ull << 20));
    ushort_t* xb    = (ushort_t*)(ws + (56ull << 20));
    ushort_t* Oat   = xb;   // alias: xb dead once gemm_qkv finishes

    xcvt<<<dim3(4096), 256, 0, stream>>>(x, xb);
    ktranspose_f2b<<<dim3(48, 16), 256, 0, stream>>>(Wqkv, WqkvT, 1024, 3072);
    ktranspose_f2b<<<dim3(16, 16), 256, 0, stream>>>(Wout, WoutT, 1024, 1024);
    gemm_qkv<<<dim3(64, 24), 256, 0, stream>>>(xb, WqkvT, Qr, Kr, Vt);
    attn_swin<<<dim3(2048), 256, 0, stream>>>(Qr, Kr, Vt, Oat);
    gemm_out<<<dim3(64, 8), 256, 0, stream>>>(Oat, WoutT, out, bout);
}

// Round 9
// 215.189 us; speedup vs baseline: 1.4585x; 1.0373x over previous
//
#include <hip/hip_runtime.h>
#include <hip/hip_bf16.h>
#include <cstdint>
#include <cstddef>

typedef __bf16 bf16_t;
typedef bf16_t bf16x8 __attribute__((ext_vector_type(8)));
typedef float f32x4 __attribute__((ext_vector_type(4)));
typedef unsigned short ushort_t;

#define T_SEQ 2048
#define DM 1024
#define NH 16
#define HD 64
#define WIN 128
// ln(10000)/32
#define ROPE_C 0.28782313662425572f
// (1/sqrt(64)) * log2(e) -- attention softmax in log2 domain
#define SCALE_LOG2E 0.18033688011112042f
// fixed softmax shift (log2 domain); softmax is shift-invariant
#define ATT_M 16.0f

__device__ __forceinline__ ushort_t f2bf(float f) {
    union { float f; unsigned u; } v; v.f = f;
    unsigned r = v.u + 0x7fff + ((v.u >> 16) & 1);
    return (ushort_t)(r >> 16);
}
__device__ __forceinline__ float sane(float v, float sent) {
    return (fabsf(v) < 1e30f) ? v : sent;
}
// Async global->LDS, 16 B per lane. LDS dest = wave-uniform base + lane*16.
__device__ __forceinline__ void gld16(const ushort_t* g, ushort_t* l) {
    __builtin_amdgcn_global_load_lds(
        (const __attribute__((address_space(1))) unsigned int*)g,
        (__attribute__((address_space(3))) unsigned int*)l, 16, 0, 0);
}

// ---------------------------------------------------------------------------
__global__ __launch_bounds__(256) void kzero_f(float* __restrict__ p) {
    size_t i = ((size_t)blockIdx.x * 256 + threadIdx.x) * 4;
    float4 z; z.x = z.y = z.z = z.w = 0.f;
    *(float4*)(p + i) = z;
}

// ---------------------------------------------------------------------------
// Fused prep: [0,4096) x fp32->bf16 copy; [4096,4864) Wqkv^T; [4864,5120) Wout^T.
// ---------------------------------------------------------------------------
__device__ __forceinline__ void trans_f2b_tile(const float* __restrict__ in,
                                               ushort_t* __restrict__ out,
                                               int R, int C, int c0, int r0) {
    __shared__ __align__(16) ushort_t tile[64][72];
    const int tid = threadIdx.x;
    const int rl = tid >> 2, q4 = tid & 3;
    const float* src = in + (size_t)(r0 + rl) * C + c0 + q4 * 16;
    ushort_t cv[16];
#pragma unroll
    for (int i = 0; i < 4; i++) {
        float4 f = *(const float4*)(src + i * 4);
        cv[i * 4 + 0] = f2bf(f.x); cv[i * 4 + 1] = f2bf(f.y);
        cv[i * 4 + 2] = f2bf(f.z); cv[i * 4 + 3] = f2bf(f.w);
    }
    *(uint4*)&tile[rl][q4 * 16]     = *(uint4*)&cv[0];
    *(uint4*)&tile[rl][q4 * 16 + 8] = *(uint4*)&cv[8];
    __syncthreads();
    const int cl = tid >> 2;
    ushort_t tmp[16];
#pragma unroll
    for (int i = 0; i < 16; i++) tmp[i] = tile[q4 * 16 + i][cl];
    ushort_t* dst = out + (size_t)(c0 + cl) * R + r0 + q4 * 16;
    *(uint4*)(dst)     = *(uint4*)&tmp[0];
    *(uint4*)(dst + 8) = *(uint4*)&tmp[8];
}

__global__ __launch_bounds__(256) void prep(const float* __restrict__ x,
                                            const float* __restrict__ Wqkv,
                                            const float* __restrict__ Wout,
                                            ushort_t* __restrict__ xb,
                                            ushort_t* __restrict__ WqkvT,
                                            ushort_t* __restrict__ WoutT) {
    const int bx = blockIdx.x;
    if (bx < 4096) {                      // x convert: 8M elements
        size_t i = ((size_t)bx * 256 + threadIdx.x) * 8;
        float4 a0 = *(const float4*)(x + i);
        float4 a1 = *(const float4*)(x + i + 4);
        ushort_t cv[8];
        cv[0] = f2bf(a0.x); cv[1] = f2bf(a0.y); cv[2] = f2bf(a0.z); cv[3] = f2bf(a0.w);
        cv[4] = f2bf(a1.x); cv[5] = f2bf(a1.y); cv[6] = f2bf(a1.z); cv[7] = f2bf(a1.w);
        *(uint4*)(xb + i) = *(uint4*)cv;
    } else if (bx < 4864) {               // Wqkv[1024][3072] -> WqkvT[3072][1024]
        int tb = bx - 4096;
        trans_f2b_tile(Wqkv, WqkvT, 1024, 3072, (tb % 48) * 64, (tb / 48) * 64);
    } else {                              // Wout[1024][1024] -> WoutT
        int tb = bx - 4864;
        trans_f2b_tile(Wout, WoutT, 1024, 1024, (tb & 15) * 64, (tb >> 4) * 64);
    }
}

// ---------------------------------------------------------------------------
// GEMM1 (m97 structure): qkv = xb[8192][1024] * WqkvT[3072][1024]^T with
// fused RoPE + head split. Q,K roped -> Qr/Kr [nh][t][64]; V written
// directly transposed -> Vt [nh][64][T] (8B-vectorized along t).
// ---------------------------------------------------------------------------
__global__ __launch_bounds__(256) void gemm_qkv(const ushort_t* __restrict__ A,
                                                const ushort_t* __restrict__ Bt,
                                                ushort_t* __restrict__ Qr,
                                                ushort_t* __restrict__ Kr,
                                                ushort_t* __restrict__ Vt) {
    __shared__ __align__(16) ushort_t As[128 * 32];
    __shared__ __align__(16) ushort_t Bs[128 * 32];
    const int m0 = blockIdx.x * 128, n0 = blockIdx.y * 128;
    const int tid = threadIdx.x;
    const int lane = tid & 63, w = tid >> 6;
    const int wm = (w & 1) * 64, wn = (w >> 1) * 64;
    const int c = lane & 15, g = lane >> 4;
    const int lrow = lane >> 2, lcol = (lane & 3) * 8;   // staging lane map
    const int ch0 = 2 * w, ch1 = 2 * w + 1;

    f32x4 acc[4][4];
#pragma unroll
    for (int mi = 0; mi < 4; mi++)
#pragma unroll
        for (int ni = 0; ni < 4; ni++)
#pragma unroll
            for (int r = 0; r < 4; r++) acc[mi][ni][r] = 0.f;

    for (int k0 = 0; k0 < 1024; k0 += 32) {
        __syncthreads();
        gld16(A  + (size_t)(m0 + ch0 * 16 + lrow) * 1024 + k0 + lcol, &As[ch0 * 512]);
        gld16(A  + (size_t)(m0 + ch1 * 16 + lrow) * 1024 + k0 + lcol, &As[ch1 * 512]);
        gld16(Bt + (size_t)(n0 + ch0 * 16 + lrow) * 1024 + k0 + lcol, &Bs[ch0 * 512]);
        gld16(Bt + (size_t)(n0 + ch1 * 16 + lrow) * 1024 + k0 + lcol, &Bs[ch1 * 512]);
        __syncthreads();
        bf16x8 af[4], bfr[4];
#pragma unroll
        for (int mi = 0; mi < 4; mi++)
            af[mi] = *(const bf16x8*)&As[(wm + mi * 16 + c) * 32 + g * 8];
#pragma unroll
        for (int ni = 0; ni < 4; ni++)
            bfr[ni] = *(const bf16x8*)&Bs[(wn + ni * 16 + c) * 32 + g * 8];
#pragma unroll
        for (int mi = 0; mi < 4; mi++)
#pragma unroll
            for (int ni = 0; ni < 4; ni++)
                acc[mi][ni] = __builtin_amdgcn_mfma_f32_16x16x32_bf16(
                    af[mi], bfr[ni], acc[mi][ni], 0, 0, 0);
    }

    const int nb = n0 + wn;             // 64-aligned wave column base
    const int sec = nb >> 10;           // 0=Q 1=K 2=V
    const int h = (nb >> 6) & 15;

    if (sec < 2) {
        ushort_t* dst = (sec == 0) ? Qr : Kr;
        const float invf0 = __expf(-(float)(c) * ROPE_C);        // pair i = c
        const float invf1 = __expf(-(float)(16 + c) * ROPE_C);   // pair i = 16+c
#pragma unroll
        for (int mi = 0; mi < 4; mi++)
#pragma unroll
            for (int r = 0; r < 4; r++) {
                int tg = m0 + wm + mi * 16 + g * 4 + r;
                int nB = tg >> 11, t = tg & (T_SEQ - 1);
                float a0 = (float)t * invf0, a1 = (float)t * invf1;
                float s0 = __sinf(a0), c0 = __cosf(a0);
                float s1 = __sinf(a1), c1 = __cosf(a1);
                size_t base = ((size_t)(nB * NH + h) * T_SEQ + t) * 64;
                float x1a = acc[mi][0][r], x2a = acc[mi][2][r];
                float x1b = acc[mi][1][r], x2b = acc[mi][3][r];
                dst[base + c]      = f2bf(sane(x1a * c0 - x2a * s0, 1e3f));
                dst[base + 16 + c] = f2bf(sane(x1b * c1 - x2b * s1, 1e3f));
                dst[base + 32 + c] = f2bf(sane(x1a * s0 + x2a * c0, 1e3f));
                dst[base + 48 + c] = f2bf(sane(x1b * s1 + x2b * c1, 1e3f));
            }
    } else {
        // V: write transposed into Vt[nh][64][T]; 4 consecutive t per store
#pragma unroll
        for (int mi = 0; mi < 4; mi++) {
            int tgb = m0 + wm + mi * 16 + g * 4;
            int nB = tgb >> 11, t = tgb & (T_SEQ - 1);
            size_t vrow = (size_t)(nB * NH + h) * 64 * T_SEQ;
#pragma unroll
            for (int ni = 0; ni < 4; ni++) {
                ushort4 pk;
                pk.x = f2bf(sane(acc[mi][ni][0], 1e3f));
                pk.y = f2bf(sane(acc[mi][ni][1], 1e3f));
                pk.z = f2bf(sane(acc[mi][ni][2], 1e3f));
                pk.w = f2bf(sane(acc[mi][ni][3], 1e3f));
                *(ushort4*)&Vt[vrow + (size_t)(ni * 16 + c) * T_SEQ + t] = pk;
            }
        }
    }
}

// ---------------------------------------------------------------------------
// Final projection: 64x128 tile (grid 128x8 = 1024 blocks -> 4/CU).
// Wave w: rows wm=(w&1)*32 (2 mi), cols wn=(w>>1)*64 (4 ni).
// ---------------------------------------------------------------------------
__global__ __launch_bounds__(256) void gemm_out(const ushort_t* __restrict__ A,
                                                const ushort_t* __restrict__ Bt,
                                                float* __restrict__ C,
                                                const float* __restrict__ bias) {
    __shared__ __align__(16) ushort_t As[64 * 32];
    __shared__ __align__(16) ushort_t Bs[128 * 32];
    const int m0 = blockIdx.x * 64, n0 = blockIdx.y * 128;
    const int tid = threadIdx.x;
    const int lane = tid & 63, w = tid >> 6;
    const int wm = (w & 1) * 32, wn = (w >> 1) * 64;
    const int c = lane & 15, g = lane >> 4;
    const int lrow = lane >> 2, lcol = (lane & 3) * 8;
    const int ch0 = 2 * w, ch1 = 2 * w + 1;

    f32x4 acc[2][4];
#pragma unroll
    for (int mi = 0; mi < 2; mi++)
#pragma unroll
        for (int ni = 0; ni < 4; ni++)
#pragma unroll
            for (int r = 0; r < 4; r++) acc[mi][ni][r] = 0.f;

    for (int k0 = 0; k0 < 1024; k0 += 32) {
        __syncthreads();
        gld16(A  + (size_t)(m0 + w * 16 + lrow) * 1024 + k0 + lcol, &As[w * 512]);
        gld16(Bt + (size_t)(n0 + ch0 * 16 + lrow) * 1024 + k0 + lcol, &Bs[ch0 * 512]);
        gld16(Bt + (size_t)(n0 + ch1 * 16 + lrow) * 1024 + k0 + lcol, &Bs[ch1 * 512]);
        __syncthreads();
        bf16x8 af[2], bfr[4];
#pragma unroll
        for (int mi = 0; mi < 2; mi++)
            af[mi] = *(const bf16x8*)&As[(wm + mi * 16 + c) * 32 + g * 8];
#pragma unroll
        for (int ni = 0; ni < 4; ni++)
            bfr[ni] = *(const bf16x8*)&Bs[(wn + ni * 16 + c) * 32 + g * 8];
#pragma unroll
        for (int mi = 0; mi < 2; mi++)
#pragma unroll
            for (int ni = 0; ni < 4; ni++)
                acc[mi][ni] = __builtin_amdgcn_mfma_f32_16x16x32_bf16(
                    af[mi], bfr[ni], acc[mi][ni], 0, 0, 0);
    }

#pragma unroll
    for (int ni = 0; ni < 4; ni++) {
        int col = n0 + wn + ni * 16 + c;
        float bv = bias[col];
#pragma unroll
        for (int mi = 0; mi < 2; mi++)
#pragma unroll
            for (int r = 0; r < 4; r++) {
                int rowi = m0 + wm + mi * 16 + g * 4 + r;
                C[(size_t)rowi * 1024 + col] = sane(acc[mi][ni][r] + bv, 1e8f);
            }
    }
}

// ---------------------------------------------------------------------------
// Cooperative sliding-window attention, 2 q-tiles per wave.
// Block = 4 waves = 128 queries of one (n,h); wave wid handles q-tiles at
// t0 = qb + wid*16 and qb + 64 + wid*16. K tile (32x64) / V^T tile (64x32)
// staged in LDS (72-el stride, 2-way banks = free), register-prefetched.
// Fixed-max softmax; lane-local row-sum; per-wave pbuf with lgkmcnt fence.
// ---------------------------------------------------------------------------
__global__ __launch_bounds__(256) void attn_swin(const ushort_t* __restrict__ Qr,
                                                 const ushort_t* __restrict__ Kr,
                                                 const ushort_t* __restrict__ Vt,
                                                 ushort_t* __restrict__ O) {
    __shared__ __align__(16) ushort_t Ks[32 * 72];
    __shared__ __align__(16) ushort_t Vs[64 * 72];
    __shared__ __align__(16) ushort_t pbuf[4][2][16 * 32];
    const int tid = threadIdx.x;
    const int wid = tid >> 6, lane = tid & 63;
    const int qb = (blockIdx.x & 15) * 128;
    const int h = (blockIdx.x >> 4) & 15, n = blockIdx.x >> 8;
    const int c = lane & 15, g = lane >> 4;
    const size_t hb = ((size_t)(n * NH + h)) * T_SEQ * 64;
    const int t0s[2] = { qb + wid * 16, qb + 64 + wid * 16 };
    // staging maps
    const int ks_row = tid >> 3, ks_col = (tid & 7) * 8;   // 32 rows x 64 el
    const int vs_row = tid >> 2, vs_col = (tid & 3) * 8;   // 64 rows x 32 el

    bf16x8 qf0[2], qf1[2];
#pragma unroll
    for (int sub = 0; sub < 2; sub++) {
        qf0[sub] = *(const bf16x8*)(Qr + hb + (size_t)(t0s[sub] + c) * 64 + g * 8);
        qf1[sub] = *(const bf16x8*)(Qr + hb + (size_t)(t0s[sub] + c) * 64 + 32 + g * 8);
    }

    f32x4 o[2][4];
    float l_r[2][4];
#pragma unroll
    for (int sub = 0; sub < 2; sub++)
#pragma unroll
        for (int i = 0; i < 4; i++) {
            l_r[sub][i] = 0.f;
#pragma unroll
            for (int r = 0; r < 4; r++) o[sub][i][r] = 0.f;
        }

    int sB_lo = qb - WIN;        if (sB_lo < 0) sB_lo = 0;
    int sB_hi = qb + 127 + WIN;  if (sB_hi > T_SEQ - 1) sB_hi = T_SEQ - 1;

    uint4 kreg = *(const uint4*)(Kr + hb + (size_t)(sB_lo + ks_row) * 64 + ks_col);
    uint4 vreg = *(const uint4*)(Vt + hb + (size_t)vs_row * T_SEQ + sB_lo + vs_col);

    for (int s0 = sB_lo; s0 <= sB_hi; s0 += 32) {
        __syncthreads();                       // LDS free (prev compute done)
        *(uint4*)&Ks[ks_row * 72 + ks_col] = kreg;
        *(uint4*)&Vs[vs_row * 72 + vs_col] = vreg;
        __syncthreads();                       // tile staged
        int s1 = s0 + 32;
        if (s1 <= sB_hi) {                     // prefetch next tile
            kreg = *(const uint4*)(Kr + hb + (size_t)(s1 + ks_row) * 64 + ks_col);
            vreg = *(const uint4*)(Vt + hb + (size_t)vs_row * T_SEQ + s1 + vs_col);
        }
        bool act[2];
#pragma unroll
        for (int sub = 0; sub < 2; sub++)
            act[sub] = !(s0 > t0s[sub] + 143 || s0 + 31 < t0s[sub] - WIN);
        if (!act[0] && !act[1]) continue;

#pragma unroll
        for (int sub = 0; sub < 2; sub++) {
            if (!act[sub]) continue;
            const int t0 = t0s[sub];
            f32x4 S[2];
#pragma unroll
            for (int sh = 0; sh < 2; sh++) {
                bf16x8 kf0 = *(const bf16x8*)&Ks[(sh * 16 + c) * 72 + g * 8];
                bf16x8 kf1 = *(const bf16x8*)&Ks[(sh * 16 + c) * 72 + 32 + g * 8];
                f32x4 z;
#pragma unroll
                for (int r = 0; r < 4; r++) z[r] = 0.f;
                z = __builtin_amdgcn_mfma_f32_16x16x32_bf16(qf0[sub], kf0, z, 0, 0, 0);
                z = __builtin_amdgcn_mfma_f32_16x16x32_bf16(qf1[sub], kf1, z, 0, 0, 0);
                S[sh] = z;
            }
            const bool interior = (s0 >= t0 - 113) && (s0 <= t0 + 97);
            ushort_t* pb = pbuf[wid][sub];
            if (interior) {
#pragma unroll
                for (int sh = 0; sh < 2; sh++)
#pragma unroll
                    for (int r = 0; r < 4; r++) {
                        float p = exp2f(S[sh][r] * SCALE_LOG2E - ATT_M);
                        l_r[sub][r] += p;
                        pb[(g * 4 + r) * 32 + sh * 16 + c] = f2bf(p);
                    }
            } else {
#pragma unroll
                for (int sh = 0; sh < 2; sh++)
#pragma unroll
                    for (int r = 0; r < 4; r++) {
                        int s = s0 + sh * 16 + c;
                        int q = t0 + g * 4 + r;
                        bool keep = (s - q >= -WIN) && (s - q <= WIN);
                        float v = keep ? S[sh][r] * SCALE_LOG2E : -1e30f;
                        float p = exp2f(v - ATT_M);     // masked -> 0
                        l_r[sub][r] += p;
                        pb[(g * 4 + r) * 32 + sh * 16 + c] = f2bf(p);
                    }
            }
        }
        // one fence for both subs' pbuf round-trips
        __asm__ volatile("s_waitcnt lgkmcnt(0)" ::: "memory");
#pragma unroll
        for (int sub = 0; sub < 2; sub++) {
            if (!act[sub]) continue;
            bf16x8 pf = *(const bf16x8*)&pbuf[wid][sub][c * 32 + g * 8];
#pragma unroll
            for (int di = 0; di < 4; di++) {
                bf16x8 vf = *(const bf16x8*)&Vs[(di * 16 + c) * 72 + g * 8];
                o[sub][di] = __builtin_amdgcn_mfma_f32_16x16x32_bf16(pf, vf, o[sub][di], 0, 0, 0);
            }
        }
        __asm__ volatile("" ::: "memory");  // keep next iter's stores below loads
    }

    // end-of-loop row-sum reduce across the 16 c-lanes, then write O
#pragma unroll
    for (int sub = 0; sub < 2; sub++) {
#pragma unroll
        for (int off = 1; off < 16; off <<= 1)
#pragma unroll
            for (int r = 0; r < 4; r++)
                l_r[sub][r] += __shfl_xor(l_r[sub][r], off, 64);
        float inv[4];
#pragma unroll
        for (int r = 0; r < 4; r++) inv[r] = __builtin_amdgcn_rcpf(l_r[sub][r]);
#pragma unroll
        for (int di = 0; di < 4; di++)
#pragma unroll
            for (int r = 0; r < 4; r++) {
                int q = t0s[sub] + g * 4 + r;
                float val = o[sub][di][r] * inv[r];
                O[((size_t)(n * T_SEQ + q)) * DM + h * 64 + di * 16 + c] =
                    f2bf(sane(val, 1e6f));
            }
    }
}

// ---------------------------------------------------------------------------
extern "C" void kernel_launch(void* const* d_in, const int* in_sizes, int n_in,
                              void* d_out, int out_size, void* d_ws, size_t ws_size,
                              hipStream_t stream) {
    const float* x    = (const float*)d_in[0];
    const float* Wqkv = (const float*)d_in[1];
    const float* Wout = (const float*)d_in[2];
    const float* bout = (const float*)d_in[3];
    float* out = (float*)d_out;

    // Workspace (all bf16), peak 72 MB:
    //   0  .. 6  MB : WqkvT [3072][1024]
    //   6  .. 8  MB : WoutT [1024][1024]
    //   8  .. 24 MB : Qr [nh][t][64]
    //   24 .. 40 MB : Kr
    //   40 .. 56 MB : Vt [nh][64][T]   (written directly by gemm_qkv)
    //   56 .. 72 MB : xb [8192][1024]  (dead after gemm_qkv; reused as Oat)
    const size_t NEED = 72ull << 20;
    if (ws_size < NEED) {
        kzero_f<<<dim3(8192), 256, 0, stream>>>(out);  // signature: absmax==ref
        return;
    }
    char* ws = (char*)d_ws;
    ushort_t* WqkvT = (ushort_t*)(ws);
    ushort_t* WoutT = (ushort_t*)(ws + (6ull << 20));
    ushort_t* Qr    = (ushort_t*)(ws + (8ull << 20));
    ushort_t* Kr    = (ushort_t*)(ws + (24ull << 20));
    ushort_t* Vt    = (ushort_t*)(ws + (40ull << 20));
    ushort_t* xb    = (ushort_t*)(ws + (56ull << 20));
    ushort_t* Oat   = xb;   // alias: xb dead once gemm_qkv finishes

    prep<<<dim3(5120), 256, 0, stream>>>(x, Wqkv, Wout, xb, WqkvT, WoutT);
    gemm_qkv<<<dim3(64, 24), 256, 0, stream>>>(xb, WqkvT, Qr, Kr, Vt);
    attn_swin<<<dim3(1024), 256, 0, stream>>>(Qr, Kr, Vt, Oat);
    gemm_out<<<dim3(128, 8), 256, 0, stream>>>(Oat, WoutT, out, bout);
}